// Round 16
// baseline (969.598 us; speedup 1.0000x reference)
//
#include <hip/hip_runtime.h>
#include <math.h>

constexpr int V_ = 50000, D_ = 128, B_ = 1024, P_ = 50;
constexpr int N_ = 51200, E_ = 51200;
constexpr long long NS_ = (long long)N_ * D_;
constexpr float SCALE_ = 12.0f;
constexpr int NBN_L = (V_ + 127) / 128;   // 391
constexpr int NBN_P = 392;                // padded row stride for partials

typedef unsigned short u16;
typedef __attribute__((ext_vector_type(8))) unsigned short u16x8;
typedef __attribute__((ext_vector_type(8))) __bf16 bf16x8;
typedef __attribute__((ext_vector_type(4))) float f32x4;

static __device__ __forceinline__ float wsum(float v) {
    #pragma unroll
    for (int o = 32; o; o >>= 1) v += __shfl_xor(v, o, 64);
    return v;
}
static __device__ __forceinline__ float wmax(float v) {
    #pragma unroll
    for (int o = 32; o; o >>= 1) v = fmaxf(v, __shfl_xor(v, o, 64));
    return v;
}
static __device__ __forceinline__ float fsig(float x) { return 1.f / (1.f + __expf(-x)); }
static __device__ __forceinline__ float ftanh(float x) { return 2.f / (1.f + __expf(-2.f * x)) - 1.f; }
static __device__ __forceinline__ u16 f2b(float x) {
    unsigned u = __float_as_uint(x);
    u += 0x7fffu + ((u >> 16) & 1u);
    return (u16)(u >> 16);
}
static __device__ __forceinline__ float b2f(u16 u) {
    return __uint_as_float(((unsigned)u) << 16);
}
static __device__ __forceinline__ float redlr(float v) {
    v += __shfl_xor(v, 1, 64); v += __shfl_xor(v, 2, 64);
    v += __shfl_xor(v, 4, 64); v += __shfl_xor(v, 8, 64);
    return v;
}

// ---------------- emb -> bf16 + rnv ----------------
__global__ void k_embcv(const float* __restrict__ emb, u16* __restrict__ embb,
                        float* __restrict__ rnv) {
    int row = blockIdx.x * 4 + (threadIdx.x >> 6);
    if (row >= V_) return;
    int l = threadIdx.x & 63;
    const float* p = emb + (long long)row * D_;
    float a = p[l], b = p[l + 64];
    float ss = wsum(a * a + b * b);
    if (l == 0) rnv[row] = 1.f / (sqrtf(ss) + 1e-12f);
    u16* q = embb + (long long)row * D_;
    q[l] = f2b(a); q[l + 64] = f2b(b);
}

// ---------------- dt = max(edge_t) ----------------
__global__ void k_dtmax(const float* __restrict__ et, float* __restrict__ dt) {
    __shared__ float s[1024];
    float m = 0.f;
    for (int i = threadIdx.x; i < E_; i += 1024) m = fmaxf(m, et[i]);
    s[threadIdx.x] = m; __syncthreads();
    for (int o = 512; o; o >>= 1) {
        if (threadIdx.x < o) s[threadIdx.x] = fmaxf(s[threadIdx.x], s[threadIdx.x + o]);
        __syncthreads();
    }
    if (threadIdx.x == 0) *dt = s[0];
}

// ---------------- feat0 (bf16 only) ----------------
__global__ void k_feat0(const u16* __restrict__ embb, const float* __restrict__ rnv,
                        const int* __restrict__ iid, u16* __restrict__ featb) {
    int row = blockIdx.x * 4 + (threadIdx.x >> 6);
    int l = threadIdx.x & 63;
    int id = iid[row];
    const u16* p = embb + (long long)id * D_;
    float s = rnv[id];
    u16* qb = featb + (long long)row * D_;
    qb[l] = f2b(b2f(p[l]) * s); qb[l + 64] = f2b(b2f(p[l + 64]) * s);
}

// ---------------- stage-A per-graph weighted aggregation ----------------
__global__ void k_aggA_g(const int* __restrict__ esrc, const int* __restrict__ edst,
                         const float* __restrict__ ew, const u16* __restrict__ featb,
                         u16* __restrict__ m_in, u16* __restrict__ m_out) {
    __shared__ float sfeat[P_ * D_];
    __shared__ float smin[P_ * D_];
    __shared__ float smout[P_ * D_];
    __shared__ int ses[P_], sed[P_];
    __shared__ float sw[P_], swin[P_], swout[P_];
    int g = blockIdx.x, t = threadIdx.x;
    int n0 = g * P_;
    long long base = (long long)n0 * D_;
    for (int i = t; i < P_ * D_; i += 256) {
        sfeat[i] = b2f(featb[base + i]);
        smin[i] = 0.f; smout[i] = 0.f;
    }
    if (t < P_) {
        int E0 = g * P_ + t;
        ses[t] = esrc[E0] - n0;
        sed[t] = edst[E0] - n0;
        sw[t] = ew[E0];
    }
    __syncthreads();
    int d = t & 127;
    for (int e = 0; e < P_; e++) {
        int ls = ses[e], ld = sed[e];
        float w = sw[e];
        if (t < 128) smin[ld * D_ + d] += sfeat[ls * D_ + d] * w;
        else         smout[ls * D_ + d] += sfeat[ld * D_ + d] * w;
    }
    if (t < P_) {
        float wi = 0.f, wo = 0.f;
        for (int e = 0; e < P_; e++) {
            if (sed[e] == t) wi += sw[e];
            if (ses[e] == t) wo += sw[e];
        }
        swin[t] = (wi > 0.f) ? 1.f / wi : 1.f;
        swout[t] = (wo > 0.f) ? 1.f / wo : 1.f;
    }
    __syncthreads();
    for (int i = t; i < P_ * D_; i += 256) {
        int n = i >> 7;
        m_in[base + i] = f2b(smin[i] * swin[n]);
        m_out[base + i] = f2b(smout[i] * swout[n]);
    }
}

// ---------------- merged weight precompute ----------------
__global__ void k_prec_all(const float* __restrict__ W1, const float* __restrict__ W2,
                           const float* __restrict__ wih, const float* __restrict__ whh,
                           const float* __restrict__ bih, const float* __restrict__ bhh,
                           const float* __restrict__ Wxr, const float* __restrict__ Wxz,
                           const float* __restrict__ Whr, const float* __restrict__ Whz,
                           const float* __restrict__ bxr, const float* __restrict__ bxz,
                           const float* __restrict__ bhr, const float* __restrict__ bhz,
                           const float* __restrict__ Wxh, const float* __restrict__ Whh,
                           const float* __restrict__ bxh, const float* __restrict__ bhh2,
                           const float* __restrict__ fcu,
                           u16* __restrict__ BM1t, u16* __restrict__ BM2t, u16* __restrict__ BM3t,
                           u16* __restrict__ Brz1, u16* __restrict__ Brz2,
                           u16* __restrict__ Bu1, u16* __restrict__ Bu2, u16* __restrict__ Bfc,
                           float* __restrict__ b512, float* __restrict__ brz,
                           float* __restrict__ bu) {
    int blk = blockIdx.x, t = threadIdx.x;
    if (blk < 512) {
        const float* W = (blk < 256) ? W1 : W2;
        int coff = (blk < 256) ? 0 : 256;
        u16* Bt = (blk < 256) ? BM1t : BM2t;
        int idx = (blk & 255) * 256 + t;
        int j = idx >> 7, k = idx & 127;
        float s = 0.f;
        if (j < 384) {
            const float* wr = W + (long long)k * 256;
            const float* ir = wih + (long long)j * 512 + coff;
            for (int c = 0; c < 256; c++) s += wr[c] * ir[c];
        }
        Bt[idx] = f2b(s);
    } else if (blk < 768) {
        int idx = (blk - 512) * 256 + t;
        int j = idx >> 7, k = idx & 127;
        float v = 0.f;
        if (j < 256) v = whh[(long long)j * 128 + k];
        else if (j >= 384) v = whh[(long long)(j - 128) * 128 + k];
        BM3t[idx] = f2b(v);
    } else if (blk < 896) {
        int idx = (blk - 768) * 256 + t;
        int c = idx >> 7, k = idx & 127;
        float v1 = (c < 128) ? Wxr[(long long)k * 128 + c] : Wxz[(long long)k * 128 + (c - 128)];
        float v2 = (c < 128) ? Whr[(long long)k * 128 + c] : Whz[(long long)k * 128 + (c - 128)];
        Brz1[idx] = f2b(v1); Brz2[idx] = f2b(v2);
        if (k == 0) brz[c] = (c < 128) ? bxr[c] + bhr[c] : bxz[c - 128] + bhz[c - 128];
    } else if (blk < 960) {
        int idx = (blk - 896) * 256 + t;
        int c = idx >> 7, k = idx & 127;
        Bu1[idx] = f2b(Wxh[(long long)k * 128 + c]);
        Bu2[idx] = f2b(Whh[(long long)k * 128 + c]);
        if (k == 0) bu[c] = bxh[c] + bhh2[c];
    } else if (blk < 1024) {
        int idx = (blk - 960) * 256 + t;
        int c = idx >> 7, k = idx & 127;
        Bfc[idx] = f2b(fcu[(long long)k * 128 + c]);
    } else {
        int j = (blk - 1024) * 256 + t;
        if (j < 512) {
            float v;
            if (j < 256) v = bih[j] + bhh[j];
            else if (j < 384) v = bih[j];
            else v = bhh[j - 128];
            b512[j] = v;
        }
    }
}

// ---------------- bf16 MFMA GEMM (stage A + FU) ----------------
template<int NSEG, int ACT>
__launch_bounds__(256)
__global__ void k_mm(const u16* __restrict__ A1, const u16* __restrict__ A2,
                     const u16* __restrict__ A3,
                     const u16* __restrict__ B1, const u16* __restrict__ B2,
                     const u16* __restrict__ B3,
                     const float* __restrict__ bias,
                     u16* __restrict__ C, int ldc, int nbn) {
    __shared__ u16 As[128 * 40];
    __shared__ u16 Bs[128 * 40];
    const int t = threadIdx.x;
    const int bid = blockIdx.x;
    const int xcd = bid & 7, idx = bid >> 3;
    const int nbm8 = gridDim.x / (8 * nbn);
    const int bm = xcd * nbm8 + idx / nbn;
    const int bn = idx % nbn;
    const int lane = t & 63, wid = t >> 6;
    const int wr = wid >> 1, wc = wid & 1;
    const int lr = lane & 15, lh = lane >> 4;
    f32x4 acc[4][4] = {};
    constexpr int KTOT = NSEG * 128;
    for (int ks = 0; ks < KTOT; ks += 32) {
        const u16* Ap = (NSEG == 1) ? A1 : (ks < 128 ? A1 : (ks < 256 ? A2 : A3));
        const u16* Bp = (NSEG == 1) ? B1 : (ks < 128 ? B1 : (ks < 256 ? B2 : B3));
        int kk = ks & 127;
        #pragma unroll
        for (int i = 0; i < 2; i++) {
            int id2 = i * 256 + t;
            int row = id2 >> 2, kl = (id2 & 3) * 8;
            u16x8 va = *(const u16x8*)&Ap[((long long)bm * 128 + row) * 128 + kk + kl];
            *(u16x8*)&As[row * 40 + kl] = va;
            u16x8 vb = *(const u16x8*)&Bp[((long long)bn * 128 + row) * 128 + kk + kl];
            *(u16x8*)&Bs[row * 40 + kl] = vb;
        }
        __syncthreads();
        bf16x8 af[4], bf[4];
        #pragma unroll
        for (int f = 0; f < 4; f++) {
            u16x8 ar = *(const u16x8*)&As[(wr * 64 + f * 16 + lr) * 40 + lh * 8];
            u16x8 br = *(const u16x8*)&Bs[(wc * 64 + f * 16 + lr) * 40 + lh * 8];
            af[f] = __builtin_bit_cast(bf16x8, ar);
            bf[f] = __builtin_bit_cast(bf16x8, br);
        }
        #pragma unroll
        for (int fr = 0; fr < 4; fr++)
            #pragma unroll
            for (int fc = 0; fc < 4; fc++)
                acc[fr][fc] = __builtin_amdgcn_mfma_f32_16x16x32_bf16(af[fr], bf[fc], acc[fr][fc], 0, 0, 0);
        __syncthreads();
    }
    #pragma unroll
    for (int fc = 0; fc < 4; fc++) {
        int col = bn * 128 + wc * 64 + fc * 16 + lr;
        float bb = bias ? bias[col] : 0.f;
        #pragma unroll
        for (int fr = 0; fr < 4; fr++) {
            int rowl = wr * 64 + fr * 16 + lh * 4;
            long long row0 = (long long)bm * 128 + rowl;
            #pragma unroll
            for (int r = 0; r < 4; r++) {
                float v = acc[fr][fc][r] + bb;
                if (ACT == 1) v = fsig(v);
                else if (ACT == 2) v = ftanh(v);
                C[(row0 + r) * (long long)ldc + col] = f2b(v);
            }
        }
    }
}

// ---------------- GRU + renorm (reads featb, writes featb and seeds Hb) ----------------
__global__ void k_gru2(const u16* __restrict__ gih, u16* __restrict__ featb,
                       u16* __restrict__ hb) {
    int row = blockIdx.x * 4 + (threadIdx.x >> 6);
    int l = threadIdx.x & 63;
    const u16* g = gih + (long long)row * 512;
    u16* fb = featb + (long long)row * 128;
    float nv[2]; float ss = 0.f;
    #pragma unroll
    for (int tq = 0; tq < 2; tq++) {
        int d = l + tq * 64;
        float r = fsig(b2f(g[d]));
        float z = fsig(b2f(g[128 + d]));
        float n = ftanh(b2f(g[256 + d]) + r * b2f(g[384 + d]));
        float fv = b2f(fb[d]);
        nv[tq] = (1.f - z) * n + z * fv;
        ss += nv[tq] * nv[tq];
    }
    ss = wsum(ss);
    float s = 1.f / fmaxf(sqrtf(ss), 1e-12f);
    u16 a = f2b(nv[0] * s), b = f2b(nv[1] * s);
    fb[l] = a; fb[l + 64] = b;
    u16* hh = hb + (long long)row * 128;
    hh[l] = a; hh[l + 64] = b;
}

// ---------------- RK4 stage body (compile-time parameterized) ----------------
// FIN: fold final combine+normalize. H_IS_X: stage 0 (h==feat; hb seeded == featb).
// SKIP: reuse CSR + sAX from previous body (stage 2). FIRST: acc = accw*kv.
template<int FIN, int H_IS_X, int SKIP, int FIRST>
static __device__ __forceinline__ void fstep_body(
    const int* __restrict__ esrc, const int* __restrict__ edst,
    const float* __restrict__ et,
    float tfac, float dt, float accw, float hfac,
    u16* __restrict__ featb, u16* __restrict__ hb,
    u16* __restrict__ RHG, u16* __restrict__ ZG, u16* __restrict__ accg,
    const u16* __restrict__ Brz1, const u16* __restrict__ Brz2,
    const float* __restrict__ brz,
    const u16* __restrict__ Bu1, const u16* __restrict__ Bu2,
    const float* __restrict__ bu,
    u16* sAX, u16* sAH, float* snrm,
    int* ses, int* sed, int* sdeg, int* soff, int* snbr,
    float (*ssqW)[64]) {
    constexpr int AS = 136;
    const int g = blockIdx.x, t = threadIdx.x;
    const int n0 = g * P_;
    const long long base = (long long)n0 * D_;
    const int wv = t >> 6, lane = t & 63;
    const int lr = lane & 15, lh = lane >> 4;
    const float tv = tfac * dt;
    const int d = t & 127, grp = t >> 7;
    const int nlo = grp * 13, nhi = (grp * 13 + 13 < P_) ? grp * 13 + 13 : P_;

    if (!SKIP) {
        // ---- CSR build ----
        if (t < P_) {
            int E0 = g * P_ + t;
            int ss_ = esrc[E0] - n0, dd = edst[E0] - n0;
            bool ml = (ss_ != dd) && (et[E0] <= tv);
            ses[t] = ml ? ss_ : -1;
            sed[t] = ml ? dd : -1;
        }
        __syncthreads();
        if (t < P_) {
            int dg = 0;
            for (int e = 0; e < P_; e++) dg += (ses[e] == t) + (sed[e] == t);
            sdeg[t] = dg;
            snrm[t] = rsqrtf(fmaxf((float)dg, 1.f));
        }
        __syncthreads();
        if (t < 64) {   // wave-parallel exclusive prefix scan of sdeg
            int v = (t < P_) ? sdeg[t] : 0;
            int inc = v;
            #pragma unroll
            for (int o = 1; o < 64; o <<= 1) {
                int u = __shfl_up(inc, o, 64);
                if (t >= o) inc += u;
            }
            if (t < P_) soff[t] = inc - v;
            if (t == P_ - 1) soff[P_] = inc;
        }
        __syncthreads();
        if (t < P_) {
            int c = soff[t];
            for (int e = 0; e < P_; e++) {
                if (ses[e] == t) snbr[c++] = sed[e];
                if (sed[e] == t) snbr[c++] = ses[e];
            }
        }
        __syncthreads();
        // ---- AX = D(feat) ----
        for (int n = nlo; n < nhi; n++) {
            float a = 0.f;
            for (int j = soff[n]; j < soff[n + 1]; j++) {
                int nb = snbr[j];
                a += b2f(featb[base + (long long)nb * D_ + d]) * snrm[nb];
            }
            sAX[n * AS + d] = f2b(a * snrm[n]);
        }
    }
    // ---- AH = D(h) ----
    if (!H_IS_X) {
        for (int n = nlo; n < nhi; n++) {
            float a = 0.f;
            for (int j = soff[n]; j < soff[n + 1]; j++) {
                int nb = snbr[j];
                a += b2f(hb[base + (long long)nb * D_ + d]) * snrm[nb];
            }
            sAH[n * AS + d] = f2b(a * snrm[n]);
        }
    }
    __syncthreads();
    // ---- rz GEMM: [AX|AH](64x256) @ (256x256); wave wv owns cols wv*32..+31 ----
    {
        const u16* A2 = H_IS_X ? sAX : sAH;
        f32x4 acc[4][2] = {};
        for (int ks = 0; ks < 256; ks += 32) {
            const u16* Ap = (ks < 128) ? sAX : A2;
            const u16* Bp = (ks < 128) ? Brz1 : Brz2;
            int kk = ks & 127;
            bf16x8 af[4], bf[2];
            #pragma unroll
            for (int f = 0; f < 4; f++) {
                u16x8 ar = *(const u16x8*)&Ap[(f * 16 + lr) * AS + kk + lh * 8];
                af[f] = __builtin_bit_cast(bf16x8, ar);
            }
            #pragma unroll
            for (int f = 0; f < 2; f++) {
                int col = wv * 32 + f * 16 + lr;
                u16x8 br = *(const u16x8*)&Bp[(long long)col * 128 + kk + lh * 8];
                bf[f] = __builtin_bit_cast(bf16x8, br);
            }
            #pragma unroll
            for (int fr = 0; fr < 4; fr++)
                #pragma unroll
                for (int fc = 0; fc < 2; fc++)
                    acc[fr][fc] = __builtin_amdgcn_mfma_f32_16x16x32_bf16(af[fr], bf[fc], acc[fr][fc], 0, 0, 0);
        }
        #pragma unroll
        for (int fc = 0; fc < 2; fc++) {
            int col = wv * 32 + fc * 16 + lr;
            float bb = brz[col];
            #pragma unroll
            for (int fr = 0; fr < 4; fr++) {
                int row0 = fr * 16 + lh * 4;
                #pragma unroll
                for (int r = 0; r < 4; r++) {
                    int row = row0 + r;
                    if (row < P_) {
                        float v = fsig(acc[fr][fc][r] + bb);
                        long long ix = base + (long long)row * D_;
                        if (col < 128) RHG[ix + col] = f2b(v * b2f(hb[ix + col]));
                        else           ZG[ix + col - 128] = f2b(v);
                    }
                }
            }
        }
    }
    __syncthreads();   // vmcnt(0) drained before barrier: RHG/ZG visible block-wide
    // ---- AH = D(rh) ----
    for (int n = nlo; n < nhi; n++) {
        float a = 0.f;
        for (int j = soff[n]; j < soff[n + 1]; j++) {
            int nb = snbr[j];
            a += b2f(RHG[base + (long long)nb * D_ + d]) * snrm[nb];
        }
        sAH[n * AS + d] = f2b(a * snrm[n]);
    }
    __syncthreads();
    // ---- u GEMM (64x128, K=256); wave grid 2 rows x 4 cols of 32 ----
    const int wr = wv >> 2, wc = wv & 3;
    f32x4 acc[2][2] = {};
    for (int ks = 0; ks < 256; ks += 32) {
        const u16* Ap = (ks < 128) ? sAX : sAH;
        const u16* Bp = (ks < 128) ? Bu1 : Bu2;
        int kk = ks & 127;
        bf16x8 af[2], bf[2];
        #pragma unroll
        for (int f = 0; f < 2; f++) {
            u16x8 ar = *(const u16x8*)&Ap[(wr * 32 + f * 16 + lr) * AS + kk + lh * 8];
            af[f] = __builtin_bit_cast(bf16x8, ar);
        }
        #pragma unroll
        for (int f = 0; f < 2; f++) {
            int col = wc * 32 + f * 16 + lr;
            u16x8 br = *(const u16x8*)&Bp[(long long)col * 128 + kk + lh * 8];
            bf[f] = __builtin_bit_cast(bf16x8, br);
        }
        #pragma unroll
        for (int fr = 0; fr < 2; fr++)
            #pragma unroll
            for (int fc = 0; fc < 2; fc++)
                acc[fr][fc] = __builtin_amdgcn_mfma_f32_16x16x32_bf16(af[fr], bf[fc], acc[fr][fc], 0, 0, 0);
    }
    float pr[2][4] = {};
    #pragma unroll
    for (int fc = 0; fc < 2; fc++) {
        int col = wc * 32 + fc * 16 + lr;
        float bb = bu[col];
        #pragma unroll
        for (int fr = 0; fr < 2; fr++) {
            int row0 = wr * 32 + fr * 16 + lh * 4;
            #pragma unroll
            for (int r = 0; r < 4; r++) {
                int row = row0 + r;
                float v = 0.f;
                if (row < P_) {
                    long long ix = base + (long long)row * D_ + col;
                    float u = ftanh(acc[fr][fc][r] + bb);
                    float z = b2f(ZG[ix]);
                    float hh = b2f(hb[ix]);
                    v = (1.f - z) * (u - hh);
                }
                acc[fr][fc][r] = v;
                pr[fr][r] += v * v;
            }
        }
    }
    #pragma unroll
    for (int fr = 0; fr < 2; fr++)
        #pragma unroll
        for (int r = 0; r < 4; r++) {
            float v = redlr(pr[fr][r]);
            if (lr == 0) ssqW[wc][wr * 32 + fr * 16 + lh * 4 + r] = v;
        }
    __syncthreads();
    if (FIN) {
        float dt6 = dt / 6.f;
        float pr2[2][4] = {};
        #pragma unroll
        for (int fr = 0; fr < 2; fr++) {
            int row0 = wr * 32 + fr * 16 + lh * 4;
            #pragma unroll
            for (int r = 0; r < 4; r++) {
                int row = row0 + r;
                float sc = 0.f;
                if (row < P_) {
                    float ssum = ssqW[0][row] + ssqW[1][row] + ssqW[2][row] + ssqW[3][row];
                    sc = 1.f / fmaxf(sqrtf(ssum), 1e-12f);
                }
                #pragma unroll
                for (int fc = 0; fc < 2; fc++) {
                    int col = wc * 32 + fc * 16 + lr;
                    float fv2 = 0.f;
                    if (row < P_) {
                        long long ix = base + (long long)row * D_ + col;
                        float kv = acc[fr][fc][r] * sc;
                        float an = b2f(accg[ix]) + accw * kv;
                        fv2 = b2f(featb[ix]) + dt6 * an;
                    }
                    acc[fr][fc][r] = fv2;
                    pr2[fr][r] += fv2 * fv2;
                }
            }
        }
        __syncthreads();
        #pragma unroll
        for (int fr = 0; fr < 2; fr++)
            #pragma unroll
            for (int r = 0; r < 4; r++) {
                float v = redlr(pr2[fr][r]);
                if (lr == 0) ssqW[wc][wr * 32 + fr * 16 + lh * 4 + r] = v;
            }
        __syncthreads();
        #pragma unroll
        for (int fr = 0; fr < 2; fr++) {
            int row0 = wr * 32 + fr * 16 + lh * 4;
            #pragma unroll
            for (int r = 0; r < 4; r++) {
                int row = row0 + r;
                if (row >= P_) continue;
                float ssum = ssqW[0][row] + ssqW[1][row] + ssqW[2][row] + ssqW[3][row];
                float s2 = 1.f / sqrtf(ssum);
                #pragma unroll
                for (int fc = 0; fc < 2; fc++) {
                    int col = wc * 32 + fc * 16 + lr;
                    featb[base + (long long)row * D_ + col] = f2b(acc[fr][fc][r] * s2);
                }
            }
        }
    } else {
        #pragma unroll
        for (int fr = 0; fr < 2; fr++) {
            int row0 = wr * 32 + fr * 16 + lh * 4;
            #pragma unroll
            for (int r = 0; r < 4; r++) {
                int row = row0 + r;
                if (row >= P_) continue;
                float ssum = ssqW[0][row] + ssqW[1][row] + ssqW[2][row] + ssqW[3][row];
                float sc = 1.f / fmaxf(sqrtf(ssum), 1e-12f);
                #pragma unroll
                for (int fc = 0; fc < 2; fc++) {
                    int col = wc * 32 + fc * 16 + lr;
                    long long ix = base + (long long)row * D_ + col;
                    float kv = acc[fr][fc][r] * sc;
                    float an = (FIRST ? 0.f : b2f(accg[ix])) + accw * kv;
                    accg[ix] = f2b(an);
                    hb[ix] = f2b(b2f(featb[ix]) + hfac * dt * kv);
                }
            }
        }
    }
}

#define FSTEP_SHARED_DECL                                              \
    __shared__ u16 sAX[64 * 136];                                      \
    __shared__ u16 sAH[64 * 136];                                      \
    __shared__ float snrm[P_];                                         \
    __shared__ int ses[P_], sed[P_], sdeg[P_], soff[P_ + 1], snbr[2 * P_]; \
    __shared__ float ssqW[4][64];                                      \
    for (int i = P_ * 136 + threadIdx.x; i < 64 * 136; i += 512) { sAX[i] = 0; sAH[i] = 0; }

// ---- stage 0 (h == feat) ----
__launch_bounds__(512, 8)
__global__ void k_fstepA(const int* __restrict__ esrc, const int* __restrict__ edst,
                         const float* __restrict__ et, const float* __restrict__ dtp,
                         u16* __restrict__ featb, u16* __restrict__ hb,
                         u16* __restrict__ RHG, u16* __restrict__ ZG, u16* __restrict__ accg,
                         const u16* __restrict__ Brz1, const u16* __restrict__ Brz2,
                         const float* __restrict__ brz,
                         const u16* __restrict__ Bu1, const u16* __restrict__ Bu2,
                         const float* __restrict__ bu) {
    FSTEP_SHARED_DECL
    const float dt = dtp[0];
    fstep_body<0, 1, 0, 1>(esrc, edst, et, 0.0f, dt, 1.f, 0.5f,
                           featb, hb, RHG, ZG, accg, Brz1, Brz2, brz, Bu1, Bu2, bu,
                           sAX, sAH, snrm, ses, sed, sdeg, soff, snbr, ssqW);
}

// ---- stages 1+2 fused (same mask, shared sAX in LDS) ----
__launch_bounds__(512, 8)
__global__ void k_fstepBC(const int* __restrict__ esrc, const int* __restrict__ edst,
                          const float* __restrict__ et, const float* __restrict__ dtp,
                          u16* __restrict__ featb, u16* __restrict__ hb,
                          u16* __restrict__ RHG, u16* __restrict__ ZG, u16* __restrict__ accg,
                          const u16* __restrict__ Brz1, const u16* __restrict__ Brz2,
                          const float* __restrict__ brz,
                          const u16* __restrict__ Bu1, const u16* __restrict__ Bu2,
                          const float* __restrict__ bu) {
    FSTEP_SHARED_DECL
    const float dt = dtp[0];
    fstep_body<0, 0, 0, 0>(esrc, edst, et, 0.5f, dt, 2.f, 0.5f,
                           featb, hb, RHG, ZG, accg, Brz1, Brz2, brz, Bu1, Bu2, bu,
                           sAX, sAH, snrm, ses, sed, sdeg, soff, snbr, ssqW);
    __syncthreads();   // hb/accg from stage 1 visible before stage 2 gathers
    fstep_body<0, 0, 1, 0>(esrc, edst, et, 0.5f, dt, 2.f, 1.0f,
                           featb, hb, RHG, ZG, accg, Brz1, Brz2, brz, Bu1, Bu2, bu,
                           sAX, sAH, snrm, ses, sed, sdeg, soff, snbr, ssqW);
}

// ---- stage 3 (FIN) ----
__launch_bounds__(512, 8)
__global__ void k_fstepD(const int* __restrict__ esrc, const int* __restrict__ edst,
                         const float* __restrict__ et, const float* __restrict__ dtp,
                         u16* __restrict__ featb, u16* __restrict__ hb,
                         u16* __restrict__ RHG, u16* __restrict__ ZG, u16* __restrict__ accg,
                         const u16* __restrict__ Brz1, const u16* __restrict__ Brz2,
                         const float* __restrict__ brz,
                         const u16* __restrict__ Bu1, const u16* __restrict__ Bu2,
                         const float* __restrict__ bu) {
    FSTEP_SHARED_DECL
    const float dt = dtp[0];
    fstep_body<1, 0, 0, 0>(esrc, edst, et, 1.0f, dt, 1.f, 0.0f,
                           featb, hb, RHG, ZG, accg, Brz1, Brz2, brz, Bu1, Bu2, bu,
                           sAX, sAH, snrm, ses, sed, sdeg, soff, snbr, ssqW);
}

// ---------------- fused readout ----------------
__launch_bounds__(256)
__global__ void k_readout(const u16* __restrict__ featb, const u16* __restrict__ FU,
                          const int* __restrict__ last,
                          const float* __restrict__ fvw, const float* __restrict__ fvbv,
                          const float* __restrict__ fce, const float* __restrict__ fsr,
                          u16* __restrict__ srb) {
    __shared__ float sfl[128], sfv[128], se[64], sal[64], sin2[256], red[2];
    int g = blockIdx.x, t = threadIdx.x;
    int n0 = g * P_;
    long long ln = last[g];
    if (t < 128) sfl[t] = b2f(featb[ln * 128 + t]);
    __syncthreads();
    if (t < 128) {
        float s = fvbv[t];
        for (int k = 0; k < 128; k++) s += sfl[k] * fvw[(long long)k * 128 + t];
        sfv[t] = s;
        sin2[t] = sfl[t];
    }
    __syncthreads();
    int wid = t >> 6, lane = t & 63;
    float fce0 = fce[lane], fce1 = fce[lane + 64];
    for (int p = wid; p < P_; p += 4) {
        const u16* fu = FU + (long long)(n0 + p) * 128;
        float x0 = b2f(fu[lane]) + sfv[lane];
        float x1 = b2f(fu[lane + 64]) + sfv[lane + 64];
        float s = fsig(x0) * fce0 + fsig(x1) * fce1;
        s = wsum(s);
        if (lane == 0) se[p] = s;
    }
    __syncthreads();
    if (t < 64) {
        float v = (t < P_) ? se[t] : -1e30f;
        float m = wmax(v);
        float ex = (t < P_) ? __expf(v - m) : 0.f;
        float ss = wsum(ex);
        if (t < P_) sal[t] = ex / ss;
    }
    __syncthreads();
    if (t < 128) {
        float s = 0.f;
        for (int p = 0; p < P_; p++)
            s += b2f(featb[(long long)(n0 + p) * 128 + t]) * sal[p];
        sin2[128 + t] = s;
    }
    __syncthreads();
    if (t < 128) {
        float s = 0.f;
        for (int k = 0; k < 256; k++) s += sin2[k] * fsr[(long long)k * 128 + t];
        float ss = wsum(s * s);
        if (lane == 0) red[t >> 6] = ss;
        __syncthreads();
        float nrm = sqrtf(red[0] + red[1]);
        srb[(long long)g * 128 + t] = f2b(s / (nrm + 1e-12f));
    } else {
        __syncthreads();
    }
}

// ---------------- logits + fixed-shift log-softmax (|logit| <= 12) ----------------
template<int PASS>
__launch_bounds__(256)
__global__ void k_logits(const u16* __restrict__ A, const u16* __restrict__ Bt,
                         const float* __restrict__ rnv, float* __restrict__ rowsumP,
                         const float* __restrict__ logz, float* __restrict__ C) {
    __shared__ u16 As[128 * 40];
    __shared__ u16 Bs[128 * 40];
    __shared__ float sredW[2][128];
    const int t = threadIdx.x;
    const int bid = blockIdx.x;
    const int xcd = bid & 7, idx = bid >> 3;
    const int bm = idx & 7, bnl = idx >> 3;
    const int bn = xcd * 49 + bnl;
    if (bn >= NBN_L) return;
    const int lane = t & 63, wid = t >> 6;
    const int wr = wid >> 1, wc = wid & 1;
    const int lr = lane & 15, lh = lane >> 4;
    f32x4 acc[4][4] = {};
    for (int ks = 0; ks < 128; ks += 32) {
        #pragma unroll
        for (int i = 0; i < 2; i++) {
            int id2 = i * 256 + t;
            int row = id2 >> 2, kl = (id2 & 3) * 8;
            u16x8 va = *(const u16x8*)&A[((long long)bm * 128 + row) * 128 + ks + kl];
            *(u16x8*)&As[row * 40 + kl] = va;
            long long gcol = (long long)bn * 128 + row;
            u16x8 vb;
            if (gcol < V_) vb = *(const u16x8*)&Bt[gcol * 128 + ks + kl];
            else vb = u16x8{0, 0, 0, 0, 0, 0, 0, 0};
            *(u16x8*)&Bs[row * 40 + kl] = vb;
        }
        __syncthreads();
        bf16x8 af[4], bf[4];
        #pragma unroll
        for (int f = 0; f < 4; f++) {
            u16x8 ar = *(const u16x8*)&As[(wr * 64 + f * 16 + lr) * 40 + lh * 8];
            u16x8 br = *(const u16x8*)&Bs[(wc * 64 + f * 16 + lr) * 40 + lh * 8];
            af[f] = __builtin_bit_cast(bf16x8, ar);
            bf[f] = __builtin_bit_cast(bf16x8, br);
        }
        #pragma unroll
        for (int fr = 0; fr < 4; fr++)
            #pragma unroll
            for (int fc = 0; fc < 4; fc++)
                acc[fr][fc] = __builtin_amdgcn_mfma_f32_16x16x32_bf16(af[fr], bf[fc], acc[fr][fc], 0, 0, 0);
        __syncthreads();
    }
    if (PASS == 0) {
        float pr[4][4] = {};
        #pragma unroll
        for (int fc = 0; fc < 4; fc++) {
            int col = bn * 128 + wc * 64 + fc * 16 + lr;
            if (col >= V_) continue;
            float cs = rnv[col] * SCALE_;
            #pragma unroll
            for (int fr = 0; fr < 4; fr++)
                #pragma unroll
                for (int r = 0; r < 4; r++)
                    pr[fr][r] += __expf(acc[fr][fc][r] * cs - SCALE_);
        }
        #pragma unroll
        for (int fr = 0; fr < 4; fr++)
            #pragma unroll
            for (int r = 0; r < 4; r++) {
                float v = redlr(pr[fr][r]);
                if (lr == 0) sredW[wc][wr * 64 + fr * 16 + lh * 4 + r] = v;
            }
        __syncthreads();
        if (t < 128) rowsumP[(long long)(bm * 128 + t) * NBN_P + bn] = sredW[0][t] + sredW[1][t];
    } else {
        if (t < 128) sredW[0][t] = logz[bm * 128 + t];
        __syncthreads();
        #pragma unroll
        for (int fc = 0; fc < 4; fc++) {
            int col = bn * 128 + wc * 64 + fc * 16 + lr;
            if (col >= V_) continue;
            float cs = rnv[col] * SCALE_;
            #pragma unroll
            for (int fr = 0; fr < 4; fr++) {
                int rowl = wr * 64 + fr * 16 + lh * 4;
                long long row0 = (long long)bm * 128 + rowl;
                #pragma unroll
                for (int r = 0; r < 4; r++)
                    C[(row0 + r) * (long long)V_ + col] = acc[fr][fc][r] * cs - SCALE_ - sredW[0][rowl + r];
            }
        }
    }
}

// reduce partials: logz[row] = log( sum_j rowsumP[row][j] )
__global__ void k_rsum(const float* __restrict__ rowsumP, float* __restrict__ logz) {
    int t = threadIdx.x;
    int row = blockIdx.x * 128 + (t >> 1);
    int half = t & 1;
    const float* p = rowsumP + (long long)row * NBN_P;
    float s = 0.f;
    int j0 = half ? 196 : 0, j1 = half ? NBN_L : 196;
    for (int j = j0; j < j1; j++) s += p[j];
    s += __shfl_xor(s, 1);
    if (!half) logz[row] = logf(s);
}

// ================= host orchestration =================
extern "C" void kernel_launch(void* const* d_in, const int* in_sizes, int n_in,
                              void* d_out, int out_size, void* d_ws, size_t ws_size,
                              hipStream_t stream) {
    const int* iid   = (const int*)d_in[0];
    const int* esrc  = (const int*)d_in[1];
    const int* edst  = (const int*)d_in[2];
    const int* last  = (const int*)d_in[4];
    const float* ew  = (const float*)d_in[5];
    const float* et  = (const float*)d_in[6];
    const float* emb = (const float*)d_in[7];
    const float* W1  = (const float*)d_in[8];
    const float* W2  = (const float*)d_in[9];
    const float* wih = (const float*)d_in[10];
    const float* whh = (const float*)d_in[11];
    const float* bih = (const float*)d_in[12];
    const float* bhh = (const float*)d_in[13];
    const float* Wxr = (const float*)d_in[14]; const float* bxr = (const float*)d_in[15];
    const float* Wxz = (const float*)d_in[16]; const float* bxz = (const float*)d_in[17];
    const float* Wxh = (const float*)d_in[18]; const float* bxh = (const float*)d_in[19];
    const float* Whr = (const float*)d_in[20]; const float* bhr = (const float*)d_in[21];
    const float* Whz = (const float*)d_in[22]; const float* bhz = (const float*)d_in[23];
    const float* Whh = (const float*)d_in[24]; const float* bhh2 = (const float*)d_in[25];
    const float* fcu = (const float*)d_in[26];
    const float* fvw = (const float*)d_in[27]; const float* fvbv = (const float*)d_in[28];
    const float* fce = (const float*)d_in[29];
    const float* fsr = (const float*)d_in[30];
    float* out = (float*)d_out;

    char* w = (char*)d_ws;
    auto alloc = [&](size_t bytes) { char* p = w; w += (bytes + 255) & ~(size_t)255; return p; };
    u16* ACCb    = (u16*)alloc(NS_ * 2);
    u16* FEATb   = (u16*)alloc(NS_ * 2);
    u16* Hb      = (u16*)alloc(NS_ * 2);
    u16* MINb    = (u16*)alloc(NS_ * 2);
    u16* MOUTb   = (u16*)alloc(NS_ * 2);
    u16* GIHb    = (u16*)alloc(NS_ * 8);    // N x 512
    u16* RHG     = GIHb + NS_;              // aliases: GIH dead after gru
    u16* ZG      = GIHb + 2 * NS_;
    u16* FUb     = MINb;                    // MINb dead after GIH gemm
    u16* embb    = (u16*)alloc((long long)V_ * 128 * 2);
    u16* srb     = (u16*)alloc(B_ * 128 * 2);
    u16* BM1t    = (u16*)alloc(512 * 128 * 2);
    u16* BM2t    = (u16*)alloc(512 * 128 * 2);
    u16* BM3t    = (u16*)alloc(512 * 128 * 2);
    u16* Brz1    = (u16*)alloc(256 * 128 * 2);
    u16* Brz2    = (u16*)alloc(256 * 128 * 2);
    u16* Bu1     = (u16*)alloc(128 * 128 * 2);
    u16* Bu2     = (u16*)alloc(128 * 128 * 2);
    u16* Bfc     = (u16*)alloc(128 * 128 * 2);
    float* b512  = (float*)alloc(512 * 4);
    float* brz   = (float*)alloc(256 * 4);
    float* bu    = (float*)alloc(128 * 4);
    float* dtp   = (float*)alloc(64 * 4);
    float* rnv   = (float*)alloc((long long)V_ * 4);
    float* rowsumP = (float*)alloc((long long)B_ * NBN_P * 4);
    float* logz  = (float*)alloc(B_ * 4);

    k_embcv<<<(V_ + 3) / 4, 256, 0, stream>>>(emb, embb, rnv);
    k_dtmax<<<1, 1024, 0, stream>>>(et, dtp);
    k_feat0<<<N_ / 4, 256, 0, stream>>>(embb, rnv, iid, FEATb);

    // ---- stage A ----
    k_aggA_g<<<B_, 256, 0, stream>>>(esrc, edst, ew, FEATb, MINb, MOUTb);
    k_prec_all<<<1026, 256, 0, stream>>>(W1, W2, wih, whh, bih, bhh,
                                         Wxr, Wxz, Whr, Whz, bxr, bxz, bhr, bhz,
                                         Wxh, Whh, bxh, bhh2, fcu,
                                         BM1t, BM2t, BM3t, Brz1, Brz2, Bu1, Bu2, Bfc,
                                         b512, brz, bu);
    k_mm<3, 0><<<1600, 256, 0, stream>>>(MINb, MOUTb, FEATb, BM1t, BM2t, BM3t, b512, GIHb, 512, 4);
    k_gru2<<<N_ / 4, 256, 0, stream>>>(GIHb, FEATb, Hb);

    // ---- stage B: RK4 in 3 dispatches (s0, s1+s2 fused, s3) ----
    k_fstepA<<<B_, 512, 0, stream>>>(esrc, edst, et, dtp, FEATb, Hb, RHG, ZG, ACCb,
                                     Brz1, Brz2, brz, Bu1, Bu2, bu);
    k_fstepBC<<<B_, 512, 0, stream>>>(esrc, edst, et, dtp, FEATb, Hb, RHG, ZG, ACCb,
                                      Brz1, Brz2, brz, Bu1, Bu2, bu);
    k_fstepD<<<B_, 512, 0, stream>>>(esrc, edst, et, dtp, FEATb, Hb, RHG, ZG, ACCb,
                                     Brz1, Brz2, brz, Bu1, Bu2, bu);

    // ---- readout ----
    k_mm<1, 0><<<400, 256, 0, stream>>>(FEATb, nullptr, nullptr, Bfc, nullptr, nullptr,
                                        nullptr, FUb, 128, 1);
    k_readout<<<B_, 256, 0, stream>>>(FEATb, FUb, last, fvw, fvbv, fce, fsr, srb);

    k_logits<0><<<3136, 256, 0, stream>>>(srb, embb, rnv, rowsumP, nullptr, nullptr);
    k_rsum<<<8, 256, 0, stream>>>(rowsumP, logz);
    k_logits<1><<<3136, 256, 0, stream>>>(srb, embb, rnv, nullptr, logz, out);
}

// Round 17
// 853.009 us; speedup vs baseline: 1.1367x; 1.1367x over previous
//
#include <hip/hip_runtime.h>
#include <math.h>

constexpr int V_ = 50000, D_ = 128, B_ = 1024, P_ = 50;
constexpr int N_ = 51200, E_ = 51200;
constexpr long long NS_ = (long long)N_ * D_;
constexpr float SCALE_ = 12.0f;
constexpr int NBN_L = (V_ + 127) / 128;   // 391
constexpr int NBN_P = 392;                // padded row stride for partials

typedef unsigned short u16;
typedef __attribute__((ext_vector_type(8))) unsigned short u16x8;
typedef __attribute__((ext_vector_type(8))) __bf16 bf16x8;
typedef __attribute__((ext_vector_type(4))) float f32x4;

static __device__ __forceinline__ float wsum(float v) {
    #pragma unroll
    for (int o = 32; o; o >>= 1) v += __shfl_xor(v, o, 64);
    return v;
}
static __device__ __forceinline__ float wmax(float v) {
    #pragma unroll
    for (int o = 32; o; o >>= 1) v = fmaxf(v, __shfl_xor(v, o, 64));
    return v;
}
static __device__ __forceinline__ float fsig(float x) { return 1.f / (1.f + __expf(-x)); }
static __device__ __forceinline__ float ftanh(float x) { return 2.f / (1.f + __expf(-2.f * x)) - 1.f; }
static __device__ __forceinline__ u16 f2b(float x) {
    unsigned u = __float_as_uint(x);
    u += 0x7fffu + ((u >> 16) & 1u);
    return (u16)(u >> 16);
}
static __device__ __forceinline__ float b2f(u16 u) {
    return __uint_as_float(((unsigned)u) << 16);
}
static __device__ __forceinline__ float redlr(float v) {
    v += __shfl_xor(v, 1, 64); v += __shfl_xor(v, 2, 64);
    v += __shfl_xor(v, 4, 64); v += __shfl_xor(v, 8, 64);
    return v;
}

// ---------------- emb -> bf16 + rnv ----------------
__global__ void k_embcv(const float* __restrict__ emb, u16* __restrict__ embb,
                        float* __restrict__ rnv) {
    int row = blockIdx.x * 4 + (threadIdx.x >> 6);
    if (row >= V_) return;
    int l = threadIdx.x & 63;
    const float* p = emb + (long long)row * D_;
    float a = p[l], b = p[l + 64];
    float ss = wsum(a * a + b * b);
    if (l == 0) rnv[row] = 1.f / (sqrtf(ss) + 1e-12f);
    u16* q = embb + (long long)row * D_;
    q[l] = f2b(a); q[l + 64] = f2b(b);
}

// ---------------- dt = max(edge_t) ----------------
__global__ void k_dtmax(const float* __restrict__ et, float* __restrict__ dt) {
    __shared__ float s[1024];
    float m = 0.f;
    for (int i = threadIdx.x; i < E_; i += 1024) m = fmaxf(m, et[i]);
    s[threadIdx.x] = m; __syncthreads();
    for (int o = 512; o; o >>= 1) {
        if (threadIdx.x < o) s[threadIdx.x] = fmaxf(s[threadIdx.x], s[threadIdx.x + o]);
        __syncthreads();
    }
    if (threadIdx.x == 0) *dt = s[0];
}

// ---------------- feat0 (bf16 only) ----------------
__global__ void k_feat0(const u16* __restrict__ embb, const float* __restrict__ rnv,
                        const int* __restrict__ iid, u16* __restrict__ featb) {
    int row = blockIdx.x * 4 + (threadIdx.x >> 6);
    int l = threadIdx.x & 63;
    int id = iid[row];
    const u16* p = embb + (long long)id * D_;
    float s = rnv[id];
    u16* qb = featb + (long long)row * D_;
    qb[l] = f2b(b2f(p[l]) * s); qb[l + 64] = f2b(b2f(p[l + 64]) * s);
}

// ---------------- stage-A per-graph weighted aggregation ----------------
__global__ void k_aggA_g(const int* __restrict__ esrc, const int* __restrict__ edst,
                         const float* __restrict__ ew, const u16* __restrict__ featb,
                         u16* __restrict__ m_in, u16* __restrict__ m_out) {
    __shared__ float sfeat[P_ * D_];
    __shared__ float smin[P_ * D_];
    __shared__ float smout[P_ * D_];
    __shared__ int ses[P_], sed[P_];
    __shared__ float sw[P_], swin[P_], swout[P_];
    int g = blockIdx.x, t = threadIdx.x;
    int n0 = g * P_;
    long long base = (long long)n0 * D_;
    for (int i = t; i < P_ * D_; i += 256) {
        sfeat[i] = b2f(featb[base + i]);
        smin[i] = 0.f; smout[i] = 0.f;
    }
    if (t < P_) {
        int E0 = g * P_ + t;
        ses[t] = esrc[E0] - n0;
        sed[t] = edst[E0] - n0;
        sw[t] = ew[E0];
    }
    __syncthreads();
    int d = t & 127;
    for (int e = 0; e < P_; e++) {
        int ls = ses[e], ld = sed[e];
        float w = sw[e];
        if (t < 128) smin[ld * D_ + d] += sfeat[ls * D_ + d] * w;
        else         smout[ls * D_ + d] += sfeat[ld * D_ + d] * w;
    }
    if (t < P_) {
        float wi = 0.f, wo = 0.f;
        for (int e = 0; e < P_; e++) {
            if (sed[e] == t) wi += sw[e];
            if (ses[e] == t) wo += sw[e];
        }
        swin[t] = (wi > 0.f) ? 1.f / wi : 1.f;
        swout[t] = (wo > 0.f) ? 1.f / wo : 1.f;
    }
    __syncthreads();
    for (int i = t; i < P_ * D_; i += 256) {
        int n = i >> 7;
        m_in[base + i] = f2b(smin[i] * swin[n]);
        m_out[base + i] = f2b(smout[i] * swout[n]);
    }
}

// ---------------- merged weight precompute ----------------
__global__ void k_prec_all(const float* __restrict__ W1, const float* __restrict__ W2,
                           const float* __restrict__ wih, const float* __restrict__ whh,
                           const float* __restrict__ bih, const float* __restrict__ bhh,
                           const float* __restrict__ Wxr, const float* __restrict__ Wxz,
                           const float* __restrict__ Whr, const float* __restrict__ Whz,
                           const float* __restrict__ bxr, const float* __restrict__ bxz,
                           const float* __restrict__ bhr, const float* __restrict__ bhz,
                           const float* __restrict__ Wxh, const float* __restrict__ Whh,
                           const float* __restrict__ bxh, const float* __restrict__ bhh2,
                           const float* __restrict__ fcu,
                           u16* __restrict__ BM1t, u16* __restrict__ BM2t, u16* __restrict__ BM3t,
                           u16* __restrict__ Brz1, u16* __restrict__ Brz2,
                           u16* __restrict__ Bu1, u16* __restrict__ Bu2, u16* __restrict__ Bfc,
                           float* __restrict__ b512, float* __restrict__ brz,
                           float* __restrict__ bu) {
    int blk = blockIdx.x, t = threadIdx.x;
    if (blk < 512) {
        const float* W = (blk < 256) ? W1 : W2;
        int coff = (blk < 256) ? 0 : 256;
        u16* Bt = (blk < 256) ? BM1t : BM2t;
        int idx = (blk & 255) * 256 + t;
        int j = idx >> 7, k = idx & 127;
        float s = 0.f;
        if (j < 384) {
            const float* wr = W + (long long)k * 256;
            const float* ir = wih + (long long)j * 512 + coff;
            for (int c = 0; c < 256; c++) s += wr[c] * ir[c];
        }
        Bt[idx] = f2b(s);
    } else if (blk < 768) {
        int idx = (blk - 512) * 256 + t;
        int j = idx >> 7, k = idx & 127;
        float v = 0.f;
        if (j < 256) v = whh[(long long)j * 128 + k];
        else if (j >= 384) v = whh[(long long)(j - 128) * 128 + k];
        BM3t[idx] = f2b(v);
    } else if (blk < 896) {
        int idx = (blk - 768) * 256 + t;
        int c = idx >> 7, k = idx & 127;
        float v1 = (c < 128) ? Wxr[(long long)k * 128 + c] : Wxz[(long long)k * 128 + (c - 128)];
        float v2 = (c < 128) ? Whr[(long long)k * 128 + c] : Whz[(long long)k * 128 + (c - 128)];
        Brz1[idx] = f2b(v1); Brz2[idx] = f2b(v2);
        if (k == 0) brz[c] = (c < 128) ? bxr[c] + bhr[c] : bxz[c - 128] + bhz[c - 128];
    } else if (blk < 960) {
        int idx = (blk - 896) * 256 + t;
        int c = idx >> 7, k = idx & 127;
        Bu1[idx] = f2b(Wxh[(long long)k * 128 + c]);
        Bu2[idx] = f2b(Whh[(long long)k * 128 + c]);
        if (k == 0) bu[c] = bxh[c] + bhh2[c];
    } else if (blk < 1024) {
        int idx = (blk - 960) * 256 + t;
        int c = idx >> 7, k = idx & 127;
        Bfc[idx] = f2b(fcu[(long long)k * 128 + c]);
    } else {
        int j = (blk - 1024) * 256 + t;
        if (j < 512) {
            float v;
            if (j < 256) v = bih[j] + bhh[j];
            else if (j < 384) v = bih[j];
            else v = bhh[j - 128];
            b512[j] = v;
        }
    }
}

// ---------------- bf16 MFMA GEMM (stage A + FU) ----------------
template<int NSEG, int ACT>
__launch_bounds__(256)
__global__ void k_mm(const u16* __restrict__ A1, const u16* __restrict__ A2,
                     const u16* __restrict__ A3,
                     const u16* __restrict__ B1, const u16* __restrict__ B2,
                     const u16* __restrict__ B3,
                     const float* __restrict__ bias,
                     u16* __restrict__ C, int ldc, int nbn) {
    __shared__ u16 As[128 * 40];
    __shared__ u16 Bs[128 * 40];
    const int t = threadIdx.x;
    const int bid = blockIdx.x;
    const int xcd = bid & 7, idx = bid >> 3;
    const int nbm8 = gridDim.x / (8 * nbn);
    const int bm = xcd * nbm8 + idx / nbn;
    const int bn = idx % nbn;
    const int lane = t & 63, wid = t >> 6;
    const int wr = wid >> 1, wc = wid & 1;
    const int lr = lane & 15, lh = lane >> 4;
    f32x4 acc[4][4] = {};
    constexpr int KTOT = NSEG * 128;
    for (int ks = 0; ks < KTOT; ks += 32) {
        const u16* Ap = (NSEG == 1) ? A1 : (ks < 128 ? A1 : (ks < 256 ? A2 : A3));
        const u16* Bp = (NSEG == 1) ? B1 : (ks < 128 ? B1 : (ks < 256 ? B2 : B3));
        int kk = ks & 127;
        #pragma unroll
        for (int i = 0; i < 2; i++) {
            int id2 = i * 256 + t;
            int row = id2 >> 2, kl = (id2 & 3) * 8;
            u16x8 va = *(const u16x8*)&Ap[((long long)bm * 128 + row) * 128 + kk + kl];
            *(u16x8*)&As[row * 40 + kl] = va;
            u16x8 vb = *(const u16x8*)&Bp[((long long)bn * 128 + row) * 128 + kk + kl];
            *(u16x8*)&Bs[row * 40 + kl] = vb;
        }
        __syncthreads();
        bf16x8 af[4], bf[4];
        #pragma unroll
        for (int f = 0; f < 4; f++) {
            u16x8 ar = *(const u16x8*)&As[(wr * 64 + f * 16 + lr) * 40 + lh * 8];
            u16x8 br = *(const u16x8*)&Bs[(wc * 64 + f * 16 + lr) * 40 + lh * 8];
            af[f] = __builtin_bit_cast(bf16x8, ar);
            bf[f] = __builtin_bit_cast(bf16x8, br);
        }
        #pragma unroll
        for (int fr = 0; fr < 4; fr++)
            #pragma unroll
            for (int fc = 0; fc < 4; fc++)
                acc[fr][fc] = __builtin_amdgcn_mfma_f32_16x16x32_bf16(af[fr], bf[fc], acc[fr][fc], 0, 0, 0);
        __syncthreads();
    }
    #pragma unroll
    for (int fc = 0; fc < 4; fc++) {
        int col = bn * 128 + wc * 64 + fc * 16 + lr;
        float bb = bias ? bias[col] : 0.f;
        #pragma unroll
        for (int fr = 0; fr < 4; fr++) {
            int rowl = wr * 64 + fr * 16 + lh * 4;
            long long row0 = (long long)bm * 128 + rowl;
            #pragma unroll
            for (int r = 0; r < 4; r++) {
                float v = acc[fr][fc][r] + bb;
                if (ACT == 1) v = fsig(v);
                else if (ACT == 2) v = ftanh(v);
                C[(row0 + r) * (long long)ldc + col] = f2b(v);
            }
        }
    }
}

// ---------------- GRU + renorm (reads featb, writes featb and seeds Hb) ----------------
__global__ void k_gru2(const u16* __restrict__ gih, u16* __restrict__ featb,
                       u16* __restrict__ hb) {
    int row = blockIdx.x * 4 + (threadIdx.x >> 6);
    int l = threadIdx.x & 63;
    const u16* g = gih + (long long)row * 512;
    u16* fb = featb + (long long)row * 128;
    float nv[2]; float ss = 0.f;
    #pragma unroll
    for (int tq = 0; tq < 2; tq++) {
        int d = l + tq * 64;
        float r = fsig(b2f(g[d]));
        float z = fsig(b2f(g[128 + d]));
        float n = ftanh(b2f(g[256 + d]) + r * b2f(g[384 + d]));
        float fv = b2f(fb[d]);
        nv[tq] = (1.f - z) * n + z * fv;
        ss += nv[tq] * nv[tq];
    }
    ss = wsum(ss);
    float s = 1.f / fmaxf(sqrtf(ss), 1e-12f);
    u16 a = f2b(nv[0] * s), b = f2b(nv[1] * s);
    fb[l] = a; fb[l + 64] = b;
    u16* hh = hb + (long long)row * 128;
    hh[l] = a; hh[l + 64] = b;
}

// ---------------- RK4 stage body (compile-time parameterized) ----------------
template<int FIN, int H_IS_X, int SKIP, int FIRST>
static __device__ __forceinline__ void fstep_body(
    const int* __restrict__ esrc, const int* __restrict__ edst,
    const float* __restrict__ et,
    float tfac, float dt, float accw, float hfac,
    u16* __restrict__ featb, u16* __restrict__ hb,
    u16* __restrict__ RHG, u16* __restrict__ ZG, u16* __restrict__ accg,
    const u16* __restrict__ Brz1, const u16* __restrict__ Brz2,
    const float* __restrict__ brz,
    const u16* __restrict__ Bu1, const u16* __restrict__ Bu2,
    const float* __restrict__ bu,
    u16* sAX, u16* sAH, float* snrm,
    int* ses, int* sed, int* sdeg, int* soff, int* snbr,
    float (*ssqW)[64]) {
    constexpr int AS = 136;
    const int g = blockIdx.x, t = threadIdx.x;
    const int n0 = g * P_;
    const long long base = (long long)n0 * D_;
    const int wv = t >> 6, lane = t & 63;
    const int lr = lane & 15, lh = lane >> 4;
    const float tv = tfac * dt;
    const int d = t & 127, grp = t >> 7;
    const int nlo = grp * 13, nhi = (grp * 13 + 13 < P_) ? grp * 13 + 13 : P_;

    if (!SKIP) {
        if (t < P_) {
            int E0 = g * P_ + t;
            int ss_ = esrc[E0] - n0, dd = edst[E0] - n0;
            bool ml = (ss_ != dd) && (et[E0] <= tv);
            ses[t] = ml ? ss_ : -1;
            sed[t] = ml ? dd : -1;
        }
        __syncthreads();
        if (t < P_) {
            int dg = 0;
            for (int e = 0; e < P_; e++) dg += (ses[e] == t) + (sed[e] == t);
            sdeg[t] = dg;
            snrm[t] = rsqrtf(fmaxf((float)dg, 1.f));
        }
        __syncthreads();
        if (t < 64) {
            int v = (t < P_) ? sdeg[t] : 0;
            int inc = v;
            #pragma unroll
            for (int o = 1; o < 64; o <<= 1) {
                int u = __shfl_up(inc, o, 64);
                if (t >= o) inc += u;
            }
            if (t < P_) soff[t] = inc - v;
            if (t == P_ - 1) soff[P_] = inc;
        }
        __syncthreads();
        if (t < P_) {
            int c = soff[t];
            for (int e = 0; e < P_; e++) {
                if (ses[e] == t) snbr[c++] = sed[e];
                if (sed[e] == t) snbr[c++] = ses[e];
            }
        }
        __syncthreads();
        for (int n = nlo; n < nhi; n++) {
            float a = 0.f;
            for (int j = soff[n]; j < soff[n + 1]; j++) {
                int nb = snbr[j];
                a += b2f(featb[base + (long long)nb * D_ + d]) * snrm[nb];
            }
            sAX[n * AS + d] = f2b(a * snrm[n]);
        }
    }
    if (!H_IS_X) {
        for (int n = nlo; n < nhi; n++) {
            float a = 0.f;
            for (int j = soff[n]; j < soff[n + 1]; j++) {
                int nb = snbr[j];
                a += b2f(hb[base + (long long)nb * D_ + d]) * snrm[nb];
            }
            sAH[n * AS + d] = f2b(a * snrm[n]);
        }
    }
    __syncthreads();
    // ---- rz GEMM ----
    {
        const u16* A2 = H_IS_X ? sAX : sAH;
        f32x4 acc[4][2] = {};
        for (int ks = 0; ks < 256; ks += 32) {
            const u16* Ap = (ks < 128) ? sAX : A2;
            const u16* Bp = (ks < 128) ? Brz1 : Brz2;
            int kk = ks & 127;
            bf16x8 af[4], bf[2];
            #pragma unroll
            for (int f = 0; f < 4; f++) {
                u16x8 ar = *(const u16x8*)&Ap[(f * 16 + lr) * AS + kk + lh * 8];
                af[f] = __builtin_bit_cast(bf16x8, ar);
            }
            #pragma unroll
            for (int f = 0; f < 2; f++) {
                int col = wv * 32 + f * 16 + lr;
                u16x8 br = *(const u16x8*)&Bp[(long long)col * 128 + kk + lh * 8];
                bf[f] = __builtin_bit_cast(bf16x8, br);
            }
            #pragma unroll
            for (int fr = 0; fr < 4; fr++)
                #pragma unroll
                for (int fc = 0; fc < 2; fc++)
                    acc[fr][fc] = __builtin_amdgcn_mfma_f32_16x16x32_bf16(af[fr], bf[fc], acc[fr][fc], 0, 0, 0);
        }
        #pragma unroll
        for (int fc = 0; fc < 2; fc++) {
            int col = wv * 32 + fc * 16 + lr;
            float bb = brz[col];
            #pragma unroll
            for (int fr = 0; fr < 4; fr++) {
                int row0 = fr * 16 + lh * 4;
                #pragma unroll
                for (int r = 0; r < 4; r++) {
                    int row = row0 + r;
                    if (row < P_) {
                        float v = fsig(acc[fr][fc][r] + bb);
                        long long ix = base + (long long)row * D_;
                        if (col < 128) RHG[ix + col] = f2b(v * b2f(hb[ix + col]));
                        else           ZG[ix + col - 128] = f2b(v);
                    }
                }
            }
        }
    }
    __syncthreads();
    // ---- AH = D(rh) ----
    for (int n = nlo; n < nhi; n++) {
        float a = 0.f;
        for (int j = soff[n]; j < soff[n + 1]; j++) {
            int nb = snbr[j];
            a += b2f(RHG[base + (long long)nb * D_ + d]) * snrm[nb];
        }
        sAH[n * AS + d] = f2b(a * snrm[n]);
    }
    __syncthreads();
    // ---- u GEMM + update ----
    const int wr = wv >> 2, wc = wv & 3;
    f32x4 acc[2][2] = {};
    for (int ks = 0; ks < 256; ks += 32) {
        const u16* Ap = (ks < 128) ? sAX : sAH;
        const u16* Bp = (ks < 128) ? Bu1 : Bu2;
        int kk = ks & 127;
        bf16x8 af[2], bf[2];
        #pragma unroll
        for (int f = 0; f < 2; f++) {
            u16x8 ar = *(const u16x8*)&Ap[(wr * 32 + f * 16 + lr) * AS + kk + lh * 8];
            af[f] = __builtin_bit_cast(bf16x8, ar);
        }
        #pragma unroll
        for (int f = 0; f < 2; f++) {
            int col = wc * 32 + f * 16 + lr;
            u16x8 br = *(const u16x8*)&Bp[(long long)col * 128 + kk + lh * 8];
            bf[f] = __builtin_bit_cast(bf16x8, br);
        }
        #pragma unroll
        for (int fr = 0; fr < 2; fr++)
            #pragma unroll
            for (int fc = 0; fc < 2; fc++)
                acc[fr][fc] = __builtin_amdgcn_mfma_f32_16x16x32_bf16(af[fr], bf[fc], acc[fr][fc], 0, 0, 0);
    }
    float pr[2][4] = {};
    #pragma unroll
    for (int fc = 0; fc < 2; fc++) {
        int col = wc * 32 + fc * 16 + lr;
        float bb = bu[col];
        #pragma unroll
        for (int fr = 0; fr < 2; fr++) {
            int row0 = wr * 32 + fr * 16 + lh * 4;
            #pragma unroll
            for (int r = 0; r < 4; r++) {
                int row = row0 + r;
                float v = 0.f;
                if (row < P_) {
                    long long ix = base + (long long)row * D_ + col;
                    float u = ftanh(acc[fr][fc][r] + bb);
                    float z = b2f(ZG[ix]);
                    float hh = b2f(hb[ix]);
                    v = (1.f - z) * (u - hh);
                }
                acc[fr][fc][r] = v;
                pr[fr][r] += v * v;
            }
        }
    }
    #pragma unroll
    for (int fr = 0; fr < 2; fr++)
        #pragma unroll
        for (int r = 0; r < 4; r++) {
            float v = redlr(pr[fr][r]);
            if (lr == 0) ssqW[wc][wr * 32 + fr * 16 + lh * 4 + r] = v;
        }
    __syncthreads();
    if (FIN) {
        float dt6 = dt / 6.f;
        float pr2[2][4] = {};
        #pragma unroll
        for (int fr = 0; fr < 2; fr++) {
            int row0 = wr * 32 + fr * 16 + lh * 4;
            #pragma unroll
            for (int r = 0; r < 4; r++) {
                int row = row0 + r;
                float sc = 0.f;
                if (row < P_) {
                    float ssum = ssqW[0][row] + ssqW[1][row] + ssqW[2][row] + ssqW[3][row];
                    sc = 1.f / fmaxf(sqrtf(ssum), 1e-12f);
                }
                #pragma unroll
                for (int fc = 0; fc < 2; fc++) {
                    int col = wc * 32 + fc * 16 + lr;
                    float fv2 = 0.f;
                    if (row < P_) {
                        long long ix = base + (long long)row * D_ + col;
                        float kv = acc[fr][fc][r] * sc;
                        float an = b2f(accg[ix]) + accw * kv;
                        fv2 = b2f(featb[ix]) + dt6 * an;
                    }
                    acc[fr][fc][r] = fv2;
                    pr2[fr][r] += fv2 * fv2;
                }
            }
        }
        __syncthreads();
        #pragma unroll
        for (int fr = 0; fr < 2; fr++)
            #pragma unroll
            for (int r = 0; r < 4; r++) {
                float v = redlr(pr2[fr][r]);
                if (lr == 0) ssqW[wc][wr * 32 + fr * 16 + lh * 4 + r] = v;
            }
        __syncthreads();
        #pragma unroll
        for (int fr = 0; fr < 2; fr++) {
            int row0 = wr * 32 + fr * 16 + lh * 4;
            #pragma unroll
            for (int r = 0; r < 4; r++) {
                int row = row0 + r;
                if (row >= P_) continue;
                float ssum = ssqW[0][row] + ssqW[1][row] + ssqW[2][row] + ssqW[3][row];
                float s2 = 1.f / sqrtf(ssum);
                #pragma unroll
                for (int fc = 0; fc < 2; fc++) {
                    int col = wc * 32 + fc * 16 + lr;
                    featb[base + (long long)row * D_ + col] = f2b(acc[fr][fc][r] * s2);
                }
            }
        }
    } else {
        #pragma unroll
        for (int fr = 0; fr < 2; fr++) {
            int row0 = wr * 32 + fr * 16 + lh * 4;
            #pragma unroll
            for (int r = 0; r < 4; r++) {
                int row = row0 + r;
                if (row >= P_) continue;
                float ssum = ssqW[0][row] + ssqW[1][row] + ssqW[2][row] + ssqW[3][row];
                float sc = 1.f / fmaxf(sqrtf(ssum), 1e-12f);
                #pragma unroll
                for (int fc = 0; fc < 2; fc++) {
                    int col = wc * 32 + fc * 16 + lr;
                    long long ix = base + (long long)row * D_ + col;
                    float kv = acc[fr][fc][r] * sc;
                    float an = (FIRST ? 0.f : b2f(accg[ix])) + accw * kv;
                    accg[ix] = f2b(an);
                    hb[ix] = f2b(b2f(featb[ix]) + hfac * dt * kv);
                }
            }
        }
    }
}

#define FSTEP_SHARED_DECL                                              \
    __shared__ u16 sAX[64 * 136];                                      \
    __shared__ u16 sAH[64 * 136];                                      \
    __shared__ float snrm[P_];                                         \
    __shared__ int ses[P_], sed[P_], sdeg[P_], soff[P_ + 1], snbr[2 * P_]; \
    __shared__ float ssqW[4][64];                                      \
    for (int i = P_ * 136 + threadIdx.x; i < 64 * 136; i += 512) { sAX[i] = 0; sAH[i] = 0; }

// ---- stage 0 (h == feat) ----
__launch_bounds__(512, 8)
__global__ void k_fstepA(const int* __restrict__ esrc, const int* __restrict__ edst,
                         const float* __restrict__ et, const float* __restrict__ dtp,
                         u16* __restrict__ featb, u16* __restrict__ hb,
                         u16* __restrict__ RHG, u16* __restrict__ ZG, u16* __restrict__ accg,
                         const u16* __restrict__ Brz1, const u16* __restrict__ Brz2,
                         const float* __restrict__ brz,
                         const u16* __restrict__ Bu1, const u16* __restrict__ Bu2,
                         const float* __restrict__ bu) {
    FSTEP_SHARED_DECL
    const float dt = dtp[0];
    fstep_body<0, 1, 0, 1>(esrc, edst, et, 0.0f, dt, 1.f, 0.5f,
                           featb, hb, RHG, ZG, accg, Brz1, Brz2, brz, Bu1, Bu2, bu,
                           sAX, sAH, snrm, ses, sed, sdeg, soff, snbr, ssqW);
}

// ---- stages 1+2 fused (relaxed launch bounds: 2 blocks/CU, VGPR <= 128) ----
__launch_bounds__(512, 4)
__global__ void k_fstepBC(const int* __restrict__ esrc, const int* __restrict__ edst,
                          const float* __restrict__ et, const float* __restrict__ dtp,
                          u16* __restrict__ featb, u16* __restrict__ hb,
                          u16* __restrict__ RHG, u16* __restrict__ ZG, u16* __restrict__ accg,
                          const u16* __restrict__ Brz1, const u16* __restrict__ Brz2,
                          const float* __restrict__ brz,
                          const u16* __restrict__ Bu1, const u16* __restrict__ Bu2,
                          const float* __restrict__ bu) {
    FSTEP_SHARED_DECL
    const float dt = dtp[0];
    fstep_body<0, 0, 0, 0>(esrc, edst, et, 0.5f, dt, 2.f, 0.5f,
                           featb, hb, RHG, ZG, accg, Brz1, Brz2, brz, Bu1, Bu2, bu,
                           sAX, sAH, snrm, ses, sed, sdeg, soff, snbr, ssqW);
    __syncthreads();   // hb/accg from stage 1 visible before stage 2 gathers
    fstep_body<0, 0, 1, 0>(esrc, edst, et, 0.5f, dt, 2.f, 1.0f,
                           featb, hb, RHG, ZG, accg, Brz1, Brz2, brz, Bu1, Bu2, bu,
                           sAX, sAH, snrm, ses, sed, sdeg, soff, snbr, ssqW);
}

// ---- stage 3 (FIN) ----
__launch_bounds__(512, 8)
__global__ void k_fstepD(const int* __restrict__ esrc, const int* __restrict__ edst,
                         const float* __restrict__ et, const float* __restrict__ dtp,
                         u16* __restrict__ featb, u16* __restrict__ hb,
                         u16* __restrict__ RHG, u16* __restrict__ ZG, u16* __restrict__ accg,
                         const u16* __restrict__ Brz1, const u16* __restrict__ Brz2,
                         const float* __restrict__ brz,
                         const u16* __restrict__ Bu1, const u16* __restrict__ Bu2,
                         const float* __restrict__ bu) {
    FSTEP_SHARED_DECL
    const float dt = dtp[0];
    fstep_body<1, 0, 0, 0>(esrc, edst, et, 1.0f, dt, 1.f, 0.0f,
                           featb, hb, RHG, ZG, accg, Brz1, Brz2, brz, Bu1, Bu2, bu,
                           sAX, sAH, snrm, ses, sed, sdeg, soff, snbr, ssqW);
}

// ---------------- fused readout ----------------
__launch_bounds__(256)
__global__ void k_readout(const u16* __restrict__ featb, const u16* __restrict__ FU,
                          const int* __restrict__ last,
                          const float* __restrict__ fvw, const float* __restrict__ fvbv,
                          const float* __restrict__ fce, const float* __restrict__ fsr,
                          u16* __restrict__ srb) {
    __shared__ float sfl[128], sfv[128], se[64], sal[64], sin2[256], red[2];
    int g = blockIdx.x, t = threadIdx.x;
    int n0 = g * P_;
    long long ln = last[g];
    if (t < 128) sfl[t] = b2f(featb[ln * 128 + t]);
    __syncthreads();
    if (t < 128) {
        float s = fvbv[t];
        for (int k = 0; k < 128; k++) s += sfl[k] * fvw[(long long)k * 128 + t];
        sfv[t] = s;
        sin2[t] = sfl[t];
    }
    __syncthreads();
    int wid = t >> 6, lane = t & 63;
    float fce0 = fce[lane], fce1 = fce[lane + 64];
    for (int p = wid; p < P_; p += 4) {
        const u16* fu = FU + (long long)(n0 + p) * 128;
        float x0 = b2f(fu[lane]) + sfv[lane];
        float x1 = b2f(fu[lane + 64]) + sfv[lane + 64];
        float s = fsig(x0) * fce0 + fsig(x1) * fce1;
        s = wsum(s);
        if (lane == 0) se[p] = s;
    }
    __syncthreads();
    if (t < 64) {
        float v = (t < P_) ? se[t] : -1e30f;
        float m = wmax(v);
        float ex = (t < P_) ? __expf(v - m) : 0.f;
        float ss = wsum(ex);
        if (t < P_) sal[t] = ex / ss;
    }
    __syncthreads();
    if (t < 128) {
        float s = 0.f;
        for (int p = 0; p < P_; p++)
            s += b2f(featb[(long long)(n0 + p) * 128 + t]) * sal[p];
        sin2[128 + t] = s;
    }
    __syncthreads();
    if (t < 128) {
        float s = 0.f;
        for (int k = 0; k < 256; k++) s += sin2[k] * fsr[(long long)k * 128 + t];
        float ss = wsum(s * s);
        if (lane == 0) red[t >> 6] = ss;
        __syncthreads();
        float nrm = sqrtf(red[0] + red[1]);
        srb[(long long)g * 128 + t] = f2b(s / (nrm + 1e-12f));
    } else {
        __syncthreads();
    }
}

// ---------------- logits + fixed-shift log-softmax (|logit| <= 12) ----------------
template<int PASS>
__launch_bounds__(256)
__global__ void k_logits(const u16* __restrict__ A, const u16* __restrict__ Bt,
                         const float* __restrict__ rnv, float* __restrict__ rowsumP,
                         const float* __restrict__ logz, float* __restrict__ C) {
    __shared__ u16 As[128 * 40];
    __shared__ u16 Bs[128 * 40];
    __shared__ float sredW[2][128];
    const int t = threadIdx.x;
    const int bid = blockIdx.x;
    const int xcd = bid & 7, idx = bid >> 3;
    const int bm = idx & 7, bnl = idx >> 3;
    const int bn = xcd * 49 + bnl;
    if (bn >= NBN_L) return;
    const int lane = t & 63, wid = t >> 6;
    const int wr = wid >> 1, wc = wid & 1;
    const int lr = lane & 15, lh = lane >> 4;
    f32x4 acc[4][4] = {};
    for (int ks = 0; ks < 128; ks += 32) {
        #pragma unroll
        for (int i = 0; i < 2; i++) {
            int id2 = i * 256 + t;
            int row = id2 >> 2, kl = (id2 & 3) * 8;
            u16x8 va = *(const u16x8*)&A[((long long)bm * 128 + row) * 128 + ks + kl];
            *(u16x8*)&As[row * 40 + kl] = va;
            long long gcol = (long long)bn * 128 + row;
            u16x8 vb;
            if (gcol < V_) vb = *(const u16x8*)&Bt[gcol * 128 + ks + kl];
            else vb = u16x8{0, 0, 0, 0, 0, 0, 0, 0};
            *(u16x8*)&Bs[row * 40 + kl] = vb;
        }
        __syncthreads();
        bf16x8 af[4], bf[4];
        #pragma unroll
        for (int f = 0; f < 4; f++) {
            u16x8 ar = *(const u16x8*)&As[(wr * 64 + f * 16 + lr) * 40 + lh * 8];
            u16x8 br = *(const u16x8*)&Bs[(wc * 64 + f * 16 + lr) * 40 + lh * 8];
            af[f] = __builtin_bit_cast(bf16x8, ar);
            bf[f] = __builtin_bit_cast(bf16x8, br);
        }
        #pragma unroll
        for (int fr = 0; fr < 4; fr++)
            #pragma unroll
            for (int fc = 0; fc < 4; fc++)
                acc[fr][fc] = __builtin_amdgcn_mfma_f32_16x16x32_bf16(af[fr], bf[fc], acc[fr][fc], 0, 0, 0);
        __syncthreads();
    }
    if (PASS == 0) {
        float pr[4][4] = {};
        #pragma unroll
        for (int fc = 0; fc < 4; fc++) {
            int col = bn * 128 + wc * 64 + fc * 16 + lr;
            if (col >= V_) continue;
            float cs = rnv[col] * SCALE_;
            #pragma unroll
            for (int fr = 0; fr < 4; fr++)
                #pragma unroll
                for (int r = 0; r < 4; r++)
                    pr[fr][r] += __expf(acc[fr][fc][r] * cs - SCALE_);
        }
        #pragma unroll
        for (int fr = 0; fr < 4; fr++)
            #pragma unroll
            for (int r = 0; r < 4; r++) {
                float v = redlr(pr[fr][r]);
                if (lr == 0) sredW[wc][wr * 64 + fr * 16 + lh * 4 + r] = v;
            }
        __syncthreads();
        if (t < 128) rowsumP[(long long)(bm * 128 + t) * NBN_P + bn] = sredW[0][t] + sredW[1][t];
    } else {
        if (t < 128) sredW[0][t] = logz[bm * 128 + t];
        __syncthreads();
        #pragma unroll
        for (int fc = 0; fc < 4; fc++) {
            int col = bn * 128 + wc * 64 + fc * 16 + lr;
            if (col >= V_) continue;
            float cs = rnv[col] * SCALE_;
            #pragma unroll
            for (int fr = 0; fr < 4; fr++) {
                int rowl = wr * 64 + fr * 16 + lh * 4;
                long long row0 = (long long)bm * 128 + rowl;
                #pragma unroll
                for (int r = 0; r < 4; r++)
                    C[(row0 + r) * (long long)V_ + col] = acc[fr][fc][r] * cs - SCALE_ - sredW[0][rowl + r];
            }
        }
    }
}

// reduce partials: logz[row] = log( sum_j rowsumP[row][j] )
__global__ void k_rsum(const float* __restrict__ rowsumP, float* __restrict__ logz) {
    int t = threadIdx.x;
    int row = blockIdx.x * 128 + (t >> 1);
    int half = t & 1;
    const float* p = rowsumP + (long long)row * NBN_P;
    float s = 0.f;
    int j0 = half ? 196 : 0, j1 = half ? NBN_L : 196;
    for (int j = j0; j < j1; j++) s += p[j];
    s += __shfl_xor(s, 1);
    if (!half) logz[row] = logf(s);
}

// ================= host orchestration =================
extern "C" void kernel_launch(void* const* d_in, const int* in_sizes, int n_in,
                              void* d_out, int out_size, void* d_ws, size_t ws_size,
                              hipStream_t stream) {
    const int* iid   = (const int*)d_in[0];
    const int* esrc  = (const int*)d_in[1];
    const int* edst  = (const int*)d_in[2];
    const int* last  = (const int*)d_in[4];
    const float* ew  = (const float*)d_in[5];
    const float* et  = (const float*)d_in[6];
    const float* emb = (const float*)d_in[7];
    const float* W1  = (const float*)d_in[8];
    const float* W2  = (const float*)d_in[9];
    const float* wih = (const float*)d_in[10];
    const float* whh = (const float*)d_in[11];
    const float* bih = (const float*)d_in[12];
    const float* bhh = (const float*)d_in[13];
    const float* Wxr = (const float*)d_in[14]; const float* bxr = (const float*)d_in[15];
    const float* Wxz = (const float*)d_in[16]; const float* bxz = (const float*)d_in[17];
    const float* Wxh = (const float*)d_in[18]; const float* bxh = (const float*)d_in[19];
    const float* Whr = (const float*)d_in[20]; const float* bhr = (const float*)d_in[21];
    const float* Whz = (const float*)d_in[22]; const float* bhz = (const float*)d_in[23];
    const float* Whh = (const float*)d_in[24]; const float* bhh2 = (const float*)d_in[25];
    const float* fcu = (const float*)d_in[26];
    const float* fvw = (const float*)d_in[27]; const float* fvbv = (const float*)d_in[28];
    const float* fce = (const float*)d_in[29];
    const float* fsr = (const float*)d_in[30];
    float* out = (float*)d_out;

    char* w = (char*)d_ws;
    auto alloc = [&](size_t bytes) { char* p = w; w += (bytes + 255) & ~(size_t)255; return p; };
    u16* ACCb    = (u16*)alloc(NS_ * 2);
    u16* FEATb   = (u16*)alloc(NS_ * 2);
    u16* Hb      = (u16*)alloc(NS_ * 2);
    u16* MINb    = (u16*)alloc(NS_ * 2);
    u16* MOUTb   = (u16*)alloc(NS_ * 2);
    u16* GIHb    = (u16*)alloc(NS_ * 8);    // N x 512
    u16* RHG     = GIHb + NS_;              // aliases: GIH dead after gru
    u16* ZG      = GIHb + 2 * NS_;
    u16* FUb     = MINb;                    // MINb dead after GIH gemm
    u16* embb    = (u16*)alloc((long long)V_ * 128 * 2);
    u16* srb     = (u16*)alloc(B_ * 128 * 2);
    u16* BM1t    = (u16*)alloc(512 * 128 * 2);
    u16* BM2t    = (u16*)alloc(512 * 128 * 2);
    u16* BM3t    = (u16*)alloc(512 * 128 * 2);
    u16* Brz1    = (u16*)alloc(256 * 128 * 2);
    u16* Brz2    = (u16*)alloc(256 * 128 * 2);
    u16* Bu1     = (u16*)alloc(128 * 128 * 2);
    u16* Bu2     = (u16*)alloc(128 * 128 * 2);
    u16* Bfc     = (u16*)alloc(128 * 128 * 2);
    float* b512  = (float*)alloc(512 * 4);
    float* brz   = (float*)alloc(256 * 4);
    float* bu    = (float*)alloc(128 * 4);
    float* dtp   = (float*)alloc(64 * 4);
    float* rnv   = (float*)alloc((long long)V_ * 4);
    float* rowsumP = (float*)alloc((long long)B_ * NBN_P * 4);
    float* logz  = (float*)alloc(B_ * 4);

    k_embcv<<<(V_ + 3) / 4, 256, 0, stream>>>(emb, embb, rnv);
    k_dtmax<<<1, 1024, 0, stream>>>(et, dtp);
    k_feat0<<<N_ / 4, 256, 0, stream>>>(embb, rnv, iid, FEATb);

    // ---- stage A ----
    k_aggA_g<<<B_, 256, 0, stream>>>(esrc, edst, ew, FEATb, MINb, MOUTb);
    k_prec_all<<<1026, 256, 0, stream>>>(W1, W2, wih, whh, bih, bhh,
                                         Wxr, Wxz, Whr, Whz, bxr, bxz, bhr, bhz,
                                         Wxh, Whh, bxh, bhh2, fcu,
                                         BM1t, BM2t, BM3t, Brz1, Brz2, Bu1, Bu2, Bfc,
                                         b512, brz, bu);
    k_mm<3, 0><<<1600, 256, 0, stream>>>(MINb, MOUTb, FEATb, BM1t, BM2t, BM3t, b512, GIHb, 512, 4);
    k_gru2<<<N_ / 4, 256, 0, stream>>>(GIHb, FEATb, Hb);

    // ---- stage B: RK4 in 3 dispatches (s0, s1+s2 fused, s3) ----
    k_fstepA<<<B_, 512, 0, stream>>>(esrc, edst, et, dtp, FEATb, Hb, RHG, ZG, ACCb,
                                     Brz1, Brz2, brz, Bu1, Bu2, bu);
    k_fstepBC<<<B_, 512, 0, stream>>>(esrc, edst, et, dtp, FEATb, Hb, RHG, ZG, ACCb,
                                      Brz1, Brz2, brz, Bu1, Bu2, bu);
    k_fstepD<<<B_, 512, 0, stream>>>(esrc, edst, et, dtp, FEATb, Hb, RHG, ZG, ACCb,
                                     Brz1, Brz2, brz, Bu1, Bu2, bu);

    // ---- readout ----
    k_mm<1, 0><<<400, 256, 0, stream>>>(FEATb, nullptr, nullptr, Bfc, nullptr, nullptr,
                                        nullptr, FUb, 128, 1);
    k_readout<<<B_, 256, 0, stream>>>(FEATb, FUb, last, fvw, fvbv, fce, fsr, srb);

    k_logits<0><<<3136, 256, 0, stream>>>(srb, embb, rnv, rowsumP, nullptr, nullptr);
    k_rsum<<<8, 256, 0, stream>>>(rowsumP, logz);
    k_logits<1><<<3136, 256, 0, stream>>>(srb, embb, rnv, nullptr, logz, out);
}

// Round 18
// 663.441 us; speedup vs baseline: 1.4615x; 1.2857x over previous
//
#include <hip/hip_runtime.h>
#include <math.h>

constexpr int V_ = 50000, D_ = 128, B_ = 1024, P_ = 50;
constexpr int N_ = 51200, E_ = 51200;
constexpr long long NS_ = (long long)N_ * D_;
constexpr float SCALE_ = 12.0f;
constexpr int NBN_L = (V_ + 127) / 128;   // 391
constexpr int NBN_P = 392;                // padded row stride for partials

typedef unsigned short u16;
typedef __attribute__((ext_vector_type(8))) unsigned short u16x8;
typedef __attribute__((ext_vector_type(8))) __bf16 bf16x8;
typedef __attribute__((ext_vector_type(4))) float f32x4;

static __device__ __forceinline__ float wsum(float v) {
    #pragma unroll
    for (int o = 32; o; o >>= 1) v += __shfl_xor(v, o, 64);
    return v;
}
static __device__ __forceinline__ float wmax(float v) {
    #pragma unroll
    for (int o = 32; o; o >>= 1) v = fmaxf(v, __shfl_xor(v, o, 64));
    return v;
}
static __device__ __forceinline__ float fsig(float x) { return 1.f / (1.f + __expf(-x)); }
static __device__ __forceinline__ float ftanh(float x) { return 2.f / (1.f + __expf(-2.f * x)) - 1.f; }
static __device__ __forceinline__ u16 f2b(float x) {
    unsigned u = __float_as_uint(x);
    u += 0x7fffu + ((u >> 16) & 1u);
    return (u16)(u >> 16);
}
static __device__ __forceinline__ float b2f(u16 u) {
    return __uint_as_float(((unsigned)u) << 16);
}
static __device__ __forceinline__ float redlr(float v) {
    v += __shfl_xor(v, 1, 64); v += __shfl_xor(v, 2, 64);
    v += __shfl_xor(v, 4, 64); v += __shfl_xor(v, 8, 64);
    return v;
}

// ---------------- emb -> bf16 + rnv ----------------
__global__ void k_embcv(const float* __restrict__ emb, u16* __restrict__ embb,
                        float* __restrict__ rnv) {
    int row = blockIdx.x * 4 + (threadIdx.x >> 6);
    if (row >= V_) return;
    int l = threadIdx.x & 63;
    const float* p = emb + (long long)row * D_;
    float a = p[l], b = p[l + 64];
    float ss = wsum(a * a + b * b);
    if (l == 0) rnv[row] = 1.f / (sqrtf(ss) + 1e-12f);
    u16* q = embb + (long long)row * D_;
    q[l] = f2b(a); q[l + 64] = f2b(b);
}

// ---------------- dt = max(edge_t) ----------------
__global__ void k_dtmax(const float* __restrict__ et, float* __restrict__ dt) {
    __shared__ float s[1024];
    float m = 0.f;
    for (int i = threadIdx.x; i < E_; i += 1024) m = fmaxf(m, et[i]);
    s[threadIdx.x] = m; __syncthreads();
    for (int o = 512; o; o >>= 1) {
        if (threadIdx.x < o) s[threadIdx.x] = fmaxf(s[threadIdx.x], s[threadIdx.x + o]);
        __syncthreads();
    }
    if (threadIdx.x == 0) *dt = s[0];
}

// ---------------- CSR precompute for the 3 masks (tfac = 0, 0.5, 1) ----------------
// Per (mask, graph): nrm[50] f32, soff[51] (padded 64) i32, snbr[100] i32.
__global__ void k_csr(const int* __restrict__ esrc, const int* __restrict__ edst,
                      const float* __restrict__ et, const float* __restrict__ dtp,
                      float* __restrict__ csr_nrm, int* __restrict__ csr_soff,
                      int* __restrict__ csr_snbr) {
    __shared__ int ses[P_], sed[P_], sdeg[P_], soff[P_ + 1];
    int mg = blockIdx.x, t = threadIdx.x;
    int mask = mg >> 10;          // / 1024
    int g = mg & 1023;
    int n0 = g * P_;
    float tfac = (mask == 0) ? 0.f : ((mask == 1) ? 0.5f : 1.f);
    float tv = tfac * dtp[0];
    if (t < P_) {
        int E0 = g * P_ + t;
        int s = esrc[E0] - n0, d = edst[E0] - n0;
        bool ml = (s != d) && (et[E0] <= tv);
        ses[t] = ml ? s : -1;
        sed[t] = ml ? d : -1;
    }
    __syncthreads();
    if (t < P_) {
        int dg = 0;
        for (int e = 0; e < P_; e++) dg += (ses[e] == t) + (sed[e] == t);
        sdeg[t] = dg;
        csr_nrm[(long long)mg * P_ + t] = rsqrtf(fmaxf((float)dg, 1.f));
    }
    __syncthreads();
    {   // wave-parallel exclusive prefix scan (block is one wave of 64)
        int v = (t < P_) ? sdeg[t] : 0;
        int inc = v;
        #pragma unroll
        for (int o = 1; o < 64; o <<= 1) {
            int u = __shfl_up(inc, o, 64);
            if (t >= o) inc += u;
        }
        if (t < P_) soff[t] = inc - v;
        if (t == P_ - 1) soff[P_] = inc;
    }
    __syncthreads();
    if (t <= P_) csr_soff[(long long)mg * 64 + t] = soff[t];
    if (t < P_) {
        int c = soff[t];
        for (int e = 0; e < P_; e++) {
            if (ses[e] == t) csr_snbr[(long long)mg * 100 + (c++)] = sed[e];
            if (sed[e] == t) csr_snbr[(long long)mg * 100 + (c++)] = ses[e];
        }
    }
}

// ---------------- feat0 (bf16 only) ----------------
__global__ void k_feat0(const u16* __restrict__ embb, const float* __restrict__ rnv,
                        const int* __restrict__ iid, u16* __restrict__ featb) {
    int row = blockIdx.x * 4 + (threadIdx.x >> 6);
    int l = threadIdx.x & 63;
    int id = iid[row];
    const u16* p = embb + (long long)id * D_;
    float s = rnv[id];
    u16* qb = featb + (long long)row * D_;
    qb[l] = f2b(b2f(p[l]) * s); qb[l + 64] = f2b(b2f(p[l + 64]) * s);
}

// ---------------- stage-A per-graph weighted aggregation ----------------
__global__ void k_aggA_g(const int* __restrict__ esrc, const int* __restrict__ edst,
                         const float* __restrict__ ew, const u16* __restrict__ featb,
                         u16* __restrict__ m_in, u16* __restrict__ m_out) {
    __shared__ float sfeat[P_ * D_];
    __shared__ float smin[P_ * D_];
    __shared__ float smout[P_ * D_];
    __shared__ int ses[P_], sed[P_];
    __shared__ float sw[P_], swin[P_], swout[P_];
    int g = blockIdx.x, t = threadIdx.x;
    int n0 = g * P_;
    long long base = (long long)n0 * D_;
    for (int i = t; i < P_ * D_; i += 256) {
        sfeat[i] = b2f(featb[base + i]);
        smin[i] = 0.f; smout[i] = 0.f;
    }
    if (t < P_) {
        int E0 = g * P_ + t;
        ses[t] = esrc[E0] - n0;
        sed[t] = edst[E0] - n0;
        sw[t] = ew[E0];
    }
    __syncthreads();
    int d = t & 127;
    for (int e = 0; e < P_; e++) {
        int ls = ses[e], ld = sed[e];
        float w = sw[e];
        if (t < 128) smin[ld * D_ + d] += sfeat[ls * D_ + d] * w;
        else         smout[ls * D_ + d] += sfeat[ld * D_ + d] * w;
    }
    if (t < P_) {
        float wi = 0.f, wo = 0.f;
        for (int e = 0; e < P_; e++) {
            if (sed[e] == t) wi += sw[e];
            if (ses[e] == t) wo += sw[e];
        }
        swin[t] = (wi > 0.f) ? 1.f / wi : 1.f;
        swout[t] = (wo > 0.f) ? 1.f / wo : 1.f;
    }
    __syncthreads();
    for (int i = t; i < P_ * D_; i += 256) {
        int n = i >> 7;
        m_in[base + i] = f2b(smin[i] * swin[n]);
        m_out[base + i] = f2b(smout[i] * swout[n]);
    }
}

// ---------------- merged weight precompute ----------------
__global__ void k_prec_all(const float* __restrict__ W1, const float* __restrict__ W2,
                           const float* __restrict__ wih, const float* __restrict__ whh,
                           const float* __restrict__ bih, const float* __restrict__ bhh,
                           const float* __restrict__ Wxr, const float* __restrict__ Wxz,
                           const float* __restrict__ Whr, const float* __restrict__ Whz,
                           const float* __restrict__ bxr, const float* __restrict__ bxz,
                           const float* __restrict__ bhr, const float* __restrict__ bhz,
                           const float* __restrict__ Wxh, const float* __restrict__ Whh,
                           const float* __restrict__ bxh, const float* __restrict__ bhh2,
                           const float* __restrict__ fcu,
                           u16* __restrict__ BM1t, u16* __restrict__ BM2t, u16* __restrict__ BM3t,
                           u16* __restrict__ Brz1, u16* __restrict__ Brz2,
                           u16* __restrict__ Bu1, u16* __restrict__ Bu2, u16* __restrict__ Bfc,
                           float* __restrict__ b512, float* __restrict__ brz,
                           float* __restrict__ bu) {
    int blk = blockIdx.x, t = threadIdx.x;
    if (blk < 512) {
        const float* W = (blk < 256) ? W1 : W2;
        int coff = (blk < 256) ? 0 : 256;
        u16* Bt = (blk < 256) ? BM1t : BM2t;
        int idx = (blk & 255) * 256 + t;
        int j = idx >> 7, k = idx & 127;
        float s = 0.f;
        if (j < 384) {
            const float* wr = W + (long long)k * 256;
            const float* ir = wih + (long long)j * 512 + coff;
            for (int c = 0; c < 256; c++) s += wr[c] * ir[c];
        }
        Bt[idx] = f2b(s);
    } else if (blk < 768) {
        int idx = (blk - 512) * 256 + t;
        int j = idx >> 7, k = idx & 127;
        float v = 0.f;
        if (j < 256) v = whh[(long long)j * 128 + k];
        else if (j >= 384) v = whh[(long long)(j - 128) * 128 + k];
        BM3t[idx] = f2b(v);
    } else if (blk < 896) {
        int idx = (blk - 768) * 256 + t;
        int c = idx >> 7, k = idx & 127;
        float v1 = (c < 128) ? Wxr[(long long)k * 128 + c] : Wxz[(long long)k * 128 + (c - 128)];
        float v2 = (c < 128) ? Whr[(long long)k * 128 + c] : Whz[(long long)k * 128 + (c - 128)];
        Brz1[idx] = f2b(v1); Brz2[idx] = f2b(v2);
        if (k == 0) brz[c] = (c < 128) ? bxr[c] + bhr[c] : bxz[c - 128] + bhz[c - 128];
    } else if (blk < 960) {
        int idx = (blk - 896) * 256 + t;
        int c = idx >> 7, k = idx & 127;
        Bu1[idx] = f2b(Wxh[(long long)k * 128 + c]);
        Bu2[idx] = f2b(Whh[(long long)k * 128 + c]);
        if (k == 0) bu[c] = bxh[c] + bhh2[c];
    } else if (blk < 1024) {
        int idx = (blk - 960) * 256 + t;
        int c = idx >> 7, k = idx & 127;
        Bfc[idx] = f2b(fcu[(long long)k * 128 + c]);
    } else {
        int j = (blk - 1024) * 256 + t;
        if (j < 512) {
            float v;
            if (j < 256) v = bih[j] + bhh[j];
            else if (j < 384) v = bih[j];
            else v = bhh[j - 128];
            b512[j] = v;
        }
    }
}

// ---------------- bf16 MFMA GEMM (stage A + FU) ----------------
template<int NSEG, int ACT>
__launch_bounds__(256)
__global__ void k_mm(const u16* __restrict__ A1, const u16* __restrict__ A2,
                     const u16* __restrict__ A3,
                     const u16* __restrict__ B1, const u16* __restrict__ B2,
                     const u16* __restrict__ B3,
                     const float* __restrict__ bias,
                     u16* __restrict__ C, int ldc, int nbn) {
    __shared__ u16 As[128 * 40];
    __shared__ u16 Bs[128 * 40];
    const int t = threadIdx.x;
    const int bid = blockIdx.x;
    const int xcd = bid & 7, idx = bid >> 3;
    const int nbm8 = gridDim.x / (8 * nbn);
    const int bm = xcd * nbm8 + idx / nbn;
    const int bn = idx % nbn;
    const int lane = t & 63, wid = t >> 6;
    const int wr = wid >> 1, wc = wid & 1;
    const int lr = lane & 15, lh = lane >> 4;
    f32x4 acc[4][4] = {};
    constexpr int KTOT = NSEG * 128;
    for (int ks = 0; ks < KTOT; ks += 32) {
        const u16* Ap = (NSEG == 1) ? A1 : (ks < 128 ? A1 : (ks < 256 ? A2 : A3));
        const u16* Bp = (NSEG == 1) ? B1 : (ks < 128 ? B1 : (ks < 256 ? B2 : B3));
        int kk = ks & 127;
        #pragma unroll
        for (int i = 0; i < 2; i++) {
            int id2 = i * 256 + t;
            int row = id2 >> 2, kl = (id2 & 3) * 8;
            u16x8 va = *(const u16x8*)&Ap[((long long)bm * 128 + row) * 128 + kk + kl];
            *(u16x8*)&As[row * 40 + kl] = va;
            u16x8 vb = *(const u16x8*)&Bp[((long long)bn * 128 + row) * 128 + kk + kl];
            *(u16x8*)&Bs[row * 40 + kl] = vb;
        }
        __syncthreads();
        bf16x8 af[4], bf[4];
        #pragma unroll
        for (int f = 0; f < 4; f++) {
            u16x8 ar = *(const u16x8*)&As[(wr * 64 + f * 16 + lr) * 40 + lh * 8];
            u16x8 br = *(const u16x8*)&Bs[(wc * 64 + f * 16 + lr) * 40 + lh * 8];
            af[f] = __builtin_bit_cast(bf16x8, ar);
            bf[f] = __builtin_bit_cast(bf16x8, br);
        }
        #pragma unroll
        for (int fr = 0; fr < 4; fr++)
            #pragma unroll
            for (int fc = 0; fc < 4; fc++)
                acc[fr][fc] = __builtin_amdgcn_mfma_f32_16x16x32_bf16(af[fr], bf[fc], acc[fr][fc], 0, 0, 0);
        __syncthreads();
    }
    #pragma unroll
    for (int fc = 0; fc < 4; fc++) {
        int col = bn * 128 + wc * 64 + fc * 16 + lr;
        float bb = bias ? bias[col] : 0.f;
        #pragma unroll
        for (int fr = 0; fr < 4; fr++) {
            int rowl = wr * 64 + fr * 16 + lh * 4;
            long long row0 = (long long)bm * 128 + rowl;
            #pragma unroll
            for (int r = 0; r < 4; r++) {
                float v = acc[fr][fc][r] + bb;
                if (ACT == 1) v = fsig(v);
                else if (ACT == 2) v = ftanh(v);
                C[(row0 + r) * (long long)ldc + col] = f2b(v);
            }
        }
    }
}

// ---------------- GRU + renorm (reads featb, writes featb and seeds Hb) ----------------
__global__ void k_gru2(const u16* __restrict__ gih, u16* __restrict__ featb,
                       u16* __restrict__ hb) {
    int row = blockIdx.x * 4 + (threadIdx.x >> 6);
    int l = threadIdx.x & 63;
    const u16* g = gih + (long long)row * 512;
    u16* fb = featb + (long long)row * 128;
    float nv[2]; float ss = 0.f;
    #pragma unroll
    for (int tq = 0; tq < 2; tq++) {
        int d = l + tq * 64;
        float r = fsig(b2f(g[d]));
        float z = fsig(b2f(g[128 + d]));
        float n = ftanh(b2f(g[256 + d]) + r * b2f(g[384 + d]));
        float fv = b2f(fb[d]);
        nv[tq] = (1.f - z) * n + z * fv;
        ss += nv[tq] * nv[tq];
    }
    ss = wsum(ss);
    float s = 1.f / fmaxf(sqrtf(ss), 1e-12f);
    u16 a = f2b(nv[0] * s), b = f2b(nv[1] * s);
    fb[l] = a; fb[l + 64] = b;
    u16* hh = hb + (long long)row * 128;
    hh[l] = a; hh[l + 64] = b;
}

// ---------------- fused per-stage RK4 kernel (512 threads, precomputed CSR) ----------
// axmode: 0 = compute AX (no store), 1 = compute + store AXg, 2 = load AXg.
// h_is_x: stage 0 (h == feat). FIN: fold final combine+normalize. ACC in bf16.
template<int FIN>
__launch_bounds__(512, 8)
__global__ void k_fstep(const float* __restrict__ csr_nrm, const int* __restrict__ csr_soff,
                        const int* __restrict__ csr_snbr, int mask,
                        const float* __restrict__ dtp,
                        int h_is_x, int axmode,
                        u16* __restrict__ featb, u16* __restrict__ hb,
                        u16* __restrict__ AXg, u16* __restrict__ RHG, u16* __restrict__ ZG,
                        u16* __restrict__ accg,
                        const u16* __restrict__ Brz1, const u16* __restrict__ Brz2,
                        const float* __restrict__ brz,
                        const u16* __restrict__ Bu1, const u16* __restrict__ Bu2,
                        const float* __restrict__ bu,
                        float accw, float hfac, int first) {
    constexpr int AS = 136;
    __shared__ u16 sAX[64 * AS];
    __shared__ u16 sAH[64 * AS];
    __shared__ float snrm[P_];
    __shared__ int soff[P_ + 1], snbr[2 * P_];
    __shared__ float ssqW[4][64];
    const int g = blockIdx.x, t = threadIdx.x;
    const int n0 = g * P_;
    const long long base = (long long)n0 * D_;
    const int wv = t >> 6, lane = t & 63;
    const int lr = lane & 15, lh = lane >> 4;
    const float dt = dtp[0];
    const long long mg = (long long)(mask * 1024 + g);

    for (int i = t; i < 64 * AS; i += 512) { sAX[i] = 0; sAH[i] = 0; }
    // ---- CSR load (precomputed) ----
    if (t < P_) snrm[t] = csr_nrm[mg * P_ + t];
    if (t <= P_) soff[t] = csr_soff[mg * 64 + t];
    if (t >= 64 && t < 64 + 2 * P_) snbr[t - 64] = csr_snbr[mg * 100 + (t - 64)];
    __syncthreads();

    const int d = t & 127, grp = t >> 7;          // 4 row-groups of 13
    const int nlo = grp * 13, nhi = (grp * 13 + 13 < P_) ? grp * 13 + 13 : P_;
    // ---- AX ----
    if (axmode == 2) {
        for (int n = nlo; n < nhi; n++)
            sAX[n * AS + d] = AXg[base + (long long)n * D_ + d];
    } else {
        for (int n = nlo; n < nhi; n++) {
            float a = 0.f;
            for (int j = soff[n]; j < soff[n + 1]; j++) {
                int nb = snbr[j];
                a += b2f(featb[base + (long long)nb * D_ + d]) * snrm[nb];
            }
            u16 v = f2b(a * snrm[n]);
            sAX[n * AS + d] = v;
            if (axmode == 1) AXg[base + (long long)n * D_ + d] = v;
        }
    }
    // ---- AH = D(h) ----
    if (!h_is_x) {
        for (int n = nlo; n < nhi; n++) {
            float a = 0.f;
            for (int j = soff[n]; j < soff[n + 1]; j++) {
                int nb = snbr[j];
                a += b2f(hb[base + (long long)nb * D_ + d]) * snrm[nb];
            }
            sAH[n * AS + d] = f2b(a * snrm[n]);
        }
    }
    __syncthreads();
    // ---- rz GEMM: [AX|AH](64x256) @ (256x256); wave wv owns cols wv*32..+31 ----
    {
        const u16* A2 = h_is_x ? sAX : sAH;
        f32x4 acc[4][2] = {};
        for (int ks = 0; ks < 256; ks += 32) {
            const u16* Ap = (ks < 128) ? sAX : A2;
            const u16* Bp = (ks < 128) ? Brz1 : Brz2;
            int kk = ks & 127;
            bf16x8 af[4], bf[2];
            #pragma unroll
            for (int f = 0; f < 4; f++) {
                u16x8 ar = *(const u16x8*)&Ap[(f * 16 + lr) * AS + kk + lh * 8];
                af[f] = __builtin_bit_cast(bf16x8, ar);
            }
            #pragma unroll
            for (int f = 0; f < 2; f++) {
                int col = wv * 32 + f * 16 + lr;
                u16x8 br = *(const u16x8*)&Bp[(long long)col * 128 + kk + lh * 8];
                bf[f] = __builtin_bit_cast(bf16x8, br);
            }
            #pragma unroll
            for (int fr = 0; fr < 4; fr++)
                #pragma unroll
                for (int fc = 0; fc < 2; fc++)
                    acc[fr][fc] = __builtin_amdgcn_mfma_f32_16x16x32_bf16(af[fr], bf[fc], acc[fr][fc], 0, 0, 0);
        }
        #pragma unroll
        for (int fc = 0; fc < 2; fc++) {
            int col = wv * 32 + fc * 16 + lr;
            float bb = brz[col];
            #pragma unroll
            for (int fr = 0; fr < 4; fr++) {
                int row0 = fr * 16 + lh * 4;
                #pragma unroll
                for (int r = 0; r < 4; r++) {
                    int row = row0 + r;
                    if (row < P_) {
                        float v = fsig(acc[fr][fc][r] + bb);
                        long long ix = base + (long long)row * D_;
                        if (col < 128) RHG[ix + col] = f2b(v * b2f(hb[ix + col]));
                        else           ZG[ix + col - 128] = f2b(v);
                    }
                }
            }
        }
    }
    __syncthreads();   // vmcnt(0) drained before barrier: RHG/ZG visible block-wide
    // ---- AH = D(rh) ----
    for (int n = nlo; n < nhi; n++) {
        float a = 0.f;
        for (int j = soff[n]; j < soff[n + 1]; j++) {
            int nb = snbr[j];
            a += b2f(RHG[base + (long long)nb * D_ + d]) * snrm[nb];
        }
        sAH[n * AS + d] = f2b(a * snrm[n]);
    }
    __syncthreads();
    // ---- u GEMM (64x128, K=256); wave grid 2 rows x 4 cols of 32 ----
    const int wr = wv >> 2, wc = wv & 3;
    f32x4 acc[2][2] = {};
    for (int ks = 0; ks < 256; ks += 32) {
        const u16* Ap = (ks < 128) ? sAX : sAH;
        const u16* Bp = (ks < 128) ? Bu1 : Bu2;
        int kk = ks & 127;
        bf16x8 af[2], bf[2];
        #pragma unroll
        for (int f = 0; f < 2; f++) {
            u16x8 ar = *(const u16x8*)&Ap[(wr * 32 + f * 16 + lr) * AS + kk + lh * 8];
            af[f] = __builtin_bit_cast(bf16x8, ar);
        }
        #pragma unroll
        for (int f = 0; f < 2; f++) {
            int col = wc * 32 + f * 16 + lr;
            u16x8 br = *(const u16x8*)&Bp[(long long)col * 128 + kk + lh * 8];
            bf[f] = __builtin_bit_cast(bf16x8, br);
        }
        #pragma unroll
        for (int fr = 0; fr < 2; fr++)
            #pragma unroll
            for (int fc = 0; fc < 2; fc++)
                acc[fr][fc] = __builtin_amdgcn_mfma_f32_16x16x32_bf16(af[fr], bf[fc], acc[fr][fc], 0, 0, 0);
    }
    float pr[2][4] = {};
    #pragma unroll
    for (int fc = 0; fc < 2; fc++) {
        int col = wc * 32 + fc * 16 + lr;
        float bb = bu[col];
        #pragma unroll
        for (int fr = 0; fr < 2; fr++) {
            int row0 = wr * 32 + fr * 16 + lh * 4;
            #pragma unroll
            for (int r = 0; r < 4; r++) {
                int row = row0 + r;
                float v = 0.f;
                if (row < P_) {
                    long long ix = base + (long long)row * D_ + col;
                    float u = ftanh(acc[fr][fc][r] + bb);
                    float z = b2f(ZG[ix]);
                    float hh = b2f(hb[ix]);
                    v = (1.f - z) * (u - hh);
                }
                acc[fr][fc][r] = v;
                pr[fr][r] += v * v;
            }
        }
    }
    #pragma unroll
    for (int fr = 0; fr < 2; fr++)
        #pragma unroll
        for (int r = 0; r < 4; r++) {
            float v = redlr(pr[fr][r]);
            if (lr == 0) ssqW[wc][wr * 32 + fr * 16 + lh * 4 + r] = v;
        }
    __syncthreads();
    if (FIN) {
        float dt6 = dt / 6.f;
        float pr2[2][4] = {};
        #pragma unroll
        for (int fr = 0; fr < 2; fr++) {
            int row0 = wr * 32 + fr * 16 + lh * 4;
            #pragma unroll
            for (int r = 0; r < 4; r++) {
                int row = row0 + r;
                float sc = 0.f;
                if (row < P_) {
                    float ssum = ssqW[0][row] + ssqW[1][row] + ssqW[2][row] + ssqW[3][row];
                    sc = 1.f / fmaxf(sqrtf(ssum), 1e-12f);
                }
                #pragma unroll
                for (int fc = 0; fc < 2; fc++) {
                    int col = wc * 32 + fc * 16 + lr;
                    float fv2 = 0.f;
                    if (row < P_) {
                        long long ix = base + (long long)row * D_ + col;
                        float kv = acc[fr][fc][r] * sc;
                        float an = b2f(accg[ix]) + accw * kv;
                        fv2 = b2f(featb[ix]) + dt6 * an;
                    }
                    acc[fr][fc][r] = fv2;
                    pr2[fr][r] += fv2 * fv2;
                }
            }
        }
        __syncthreads();
        #pragma unroll
        for (int fr = 0; fr < 2; fr++)
            #pragma unroll
            for (int r = 0; r < 4; r++) {
                float v = redlr(pr2[fr][r]);
                if (lr == 0) ssqW[wc][wr * 32 + fr * 16 + lh * 4 + r] = v;
            }
        __syncthreads();
        #pragma unroll
        for (int fr = 0; fr < 2; fr++) {
            int row0 = wr * 32 + fr * 16 + lh * 4;
            #pragma unroll
            for (int r = 0; r < 4; r++) {
                int row = row0 + r;
                if (row >= P_) continue;
                float ssum = ssqW[0][row] + ssqW[1][row] + ssqW[2][row] + ssqW[3][row];
                float s2 = 1.f / sqrtf(ssum);
                #pragma unroll
                for (int fc = 0; fc < 2; fc++) {
                    int col = wc * 32 + fc * 16 + lr;
                    featb[base + (long long)row * D_ + col] = f2b(acc[fr][fc][r] * s2);
                }
            }
        }
    } else {
        #pragma unroll
        for (int fr = 0; fr < 2; fr++) {
            int row0 = wr * 32 + fr * 16 + lh * 4;
            #pragma unroll
            for (int r = 0; r < 4; r++) {
                int row = row0 + r;
                if (row >= P_) continue;
                float ssum = ssqW[0][row] + ssqW[1][row] + ssqW[2][row] + ssqW[3][row];
                float sc = 1.f / fmaxf(sqrtf(ssum), 1e-12f);
                #pragma unroll
                for (int fc = 0; fc < 2; fc++) {
                    int col = wc * 32 + fc * 16 + lr;
                    long long ix = base + (long long)row * D_ + col;
                    float kv = acc[fr][fc][r] * sc;
                    float an = (first ? 0.f : b2f(accg[ix])) + accw * kv;
                    accg[ix] = f2b(an);
                    hb[ix] = f2b(b2f(featb[ix]) + hfac * dt * kv);
                }
            }
        }
    }
}

// ---------------- fused readout ----------------
__launch_bounds__(256)
__global__ void k_readout(const u16* __restrict__ featb, const u16* __restrict__ FU,
                          const int* __restrict__ last,
                          const float* __restrict__ fvw, const float* __restrict__ fvbv,
                          const float* __restrict__ fce, const float* __restrict__ fsr,
                          u16* __restrict__ srb) {
    __shared__ float sfl[128], sfv[128], se[64], sal[64], sin2[256], red[2];
    int g = blockIdx.x, t = threadIdx.x;
    int n0 = g * P_;
    long long ln = last[g];
    if (t < 128) sfl[t] = b2f(featb[ln * 128 + t]);
    __syncthreads();
    if (t < 128) {
        float s = fvbv[t];
        for (int k = 0; k < 128; k++) s += sfl[k] * fvw[(long long)k * 128 + t];
        sfv[t] = s;
        sin2[t] = sfl[t];
    }
    __syncthreads();
    int wid = t >> 6, lane = t & 63;
    float fce0 = fce[lane], fce1 = fce[lane + 64];
    for (int p = wid; p < P_; p += 4) {
        const u16* fu = FU + (long long)(n0 + p) * 128;
        float x0 = b2f(fu[lane]) + sfv[lane];
        float x1 = b2f(fu[lane + 64]) + sfv[lane + 64];
        float s = fsig(x0) * fce0 + fsig(x1) * fce1;
        s = wsum(s);
        if (lane == 0) se[p] = s;
    }
    __syncthreads();
    if (t < 64) {
        float v = (t < P_) ? se[t] : -1e30f;
        float m = wmax(v);
        float ex = (t < P_) ? __expf(v - m) : 0.f;
        float ss = wsum(ex);
        if (t < P_) sal[t] = ex / ss;
    }
    __syncthreads();
    if (t < 128) {
        float s = 0.f;
        for (int p = 0; p < P_; p++)
            s += b2f(featb[(long long)(n0 + p) * 128 + t]) * sal[p];
        sin2[128 + t] = s;
    }
    __syncthreads();
    if (t < 128) {
        float s = 0.f;
        for (int k = 0; k < 256; k++) s += sin2[k] * fsr[(long long)k * 128 + t];
        float ss = wsum(s * s);
        if (lane == 0) red[t >> 6] = ss;
        __syncthreads();
        float nrm = sqrtf(red[0] + red[1]);
        srb[(long long)g * 128 + t] = f2b(s / (nrm + 1e-12f));
    } else {
        __syncthreads();
    }
}

// ---------------- logits + fixed-shift log-softmax (|logit| <= 12) ----------------
template<int PASS>
__launch_bounds__(256)
__global__ void k_logits(const u16* __restrict__ A, const u16* __restrict__ Bt,
                         const float* __restrict__ rnv, float* __restrict__ rowsumP,
                         const float* __restrict__ logz, float* __restrict__ C) {
    __shared__ u16 As[128 * 40];
    __shared__ u16 Bs[128 * 40];
    __shared__ float sredW[2][128];
    const int t = threadIdx.x;
    const int bid = blockIdx.x;
    const int xcd = bid & 7, idx = bid >> 3;
    const int bm = idx & 7, bnl = idx >> 3;
    const int bn = xcd * 49 + bnl;
    if (bn >= NBN_L) return;
    const int lane = t & 63, wid = t >> 6;
    const int wr = wid >> 1, wc = wid & 1;
    const int lr = lane & 15, lh = lane >> 4;
    f32x4 acc[4][4] = {};
    for (int ks = 0; ks < 128; ks += 32) {
        #pragma unroll
        for (int i = 0; i < 2; i++) {
            int id2 = i * 256 + t;
            int row = id2 >> 2, kl = (id2 & 3) * 8;
            u16x8 va = *(const u16x8*)&A[((long long)bm * 128 + row) * 128 + ks + kl];
            *(u16x8*)&As[row * 40 + kl] = va;
            long long gcol = (long long)bn * 128 + row;
            u16x8 vb;
            if (gcol < V_) vb = *(const u16x8*)&Bt[gcol * 128 + ks + kl];
            else vb = u16x8{0, 0, 0, 0, 0, 0, 0, 0};
            *(u16x8*)&Bs[row * 40 + kl] = vb;
        }
        __syncthreads();
        bf16x8 af[4], bf[4];
        #pragma unroll
        for (int f = 0; f < 4; f++) {
            u16x8 ar = *(const u16x8*)&As[(wr * 64 + f * 16 + lr) * 40 + lh * 8];
            u16x8 br = *(const u16x8*)&Bs[(wc * 64 + f * 16 + lr) * 40 + lh * 8];
            af[f] = __builtin_bit_cast(bf16x8, ar);
            bf[f] = __builtin_bit_cast(bf16x8, br);
        }
        #pragma unroll
        for (int fr = 0; fr < 4; fr++)
            #pragma unroll
            for (int fc = 0; fc < 4; fc++)
                acc[fr][fc] = __builtin_amdgcn_mfma_f32_16x16x32_bf16(af[fr], bf[fc], acc[fr][fc], 0, 0, 0);
        __syncthreads();
    }
    if (PASS == 0) {
        float pr[4][4] = {};
        #pragma unroll
        for (int fc = 0; fc < 4; fc++) {
            int col = bn * 128 + wc * 64 + fc * 16 + lr;
            if (col >= V_) continue;
            float cs = rnv[col] * SCALE_;
            #pragma unroll
            for (int fr = 0; fr < 4; fr++)
                #pragma unroll
                for (int r = 0; r < 4; r++)
                    pr[fr][r] += __expf(acc[fr][fc][r] * cs - SCALE_);
        }
        #pragma unroll
        for (int fr = 0; fr < 4; fr++)
            #pragma unroll
            for (int r = 0; r < 4; r++) {
                float v = redlr(pr[fr][r]);
                if (lr == 0) sredW[wc][wr * 64 + fr * 16 + lh * 4 + r] = v;
            }
        __syncthreads();
        if (t < 128) rowsumP[(long long)(bm * 128 + t) * NBN_P + bn] = sredW[0][t] + sredW[1][t];
    } else {
        if (t < 128) sredW[0][t] = logz[bm * 128 + t];
        __syncthreads();
        #pragma unroll
        for (int fc = 0; fc < 4; fc++) {
            int col = bn * 128 + wc * 64 + fc * 16 + lr;
            if (col >= V_) continue;
            float cs = rnv[col] * SCALE_;
            #pragma unroll
            for (int fr = 0; fr < 4; fr++) {
                int rowl = wr * 64 + fr * 16 + lh * 4;
                long long row0 = (long long)bm * 128 + rowl;
                #pragma unroll
                for (int r = 0; r < 4; r++)
                    C[(row0 + r) * (long long)V_ + col] = acc[fr][fc][r] * cs - SCALE_ - sredW[0][rowl + r];
            }
        }
    }
}

// reduce partials: logz[row] = log( sum_j rowsumP[row][j] )
__global__ void k_rsum(const float* __restrict__ rowsumP, float* __restrict__ logz) {
    int t = threadIdx.x;
    int row = blockIdx.x * 128 + (t >> 1);
    int half = t & 1;
    const float* p = rowsumP + (long long)row * NBN_P;
    float s = 0.f;
    int j0 = half ? 196 : 0, j1 = half ? NBN_L : 196;
    for (int j = j0; j < j1; j++) s += p[j];
    s += __shfl_xor(s, 1);
    if (!half) logz[row] = logf(s);
}

// ================= host orchestration =================
extern "C" void kernel_launch(void* const* d_in, const int* in_sizes, int n_in,
                              void* d_out, int out_size, void* d_ws, size_t ws_size,
                              hipStream_t stream) {
    const int* iid   = (const int*)d_in[0];
    const int* esrc  = (const int*)d_in[1];
    const int* edst  = (const int*)d_in[2];
    const int* last  = (const int*)d_in[4];
    const float* ew  = (const float*)d_in[5];
    const float* et  = (const float*)d_in[6];
    const float* emb = (const float*)d_in[7];
    const float* W1  = (const float*)d_in[8];
    const float* W2  = (const float*)d_in[9];
    const float* wih = (const float*)d_in[10];
    const float* whh = (const float*)d_in[11];
    const float* bih = (const float*)d_in[12];
    const float* bhh = (const float*)d_in[13];
    const float* Wxr = (const float*)d_in[14]; const float* bxr = (const float*)d_in[15];
    const float* Wxz = (const float*)d_in[16]; const float* bxz = (const float*)d_in[17];
    const float* Wxh = (const float*)d_in[18]; const float* bxh = (const float*)d_in[19];
    const float* Whr = (const float*)d_in[20]; const float* bhr = (const float*)d_in[21];
    const float* Whz = (const float*)d_in[22]; const float* bhz = (const float*)d_in[23];
    const float* Whh = (const float*)d_in[24]; const float* bhh2 = (const float*)d_in[25];
    const float* fcu = (const float*)d_in[26];
    const float* fvw = (const float*)d_in[27]; const float* fvbv = (const float*)d_in[28];
    const float* fce = (const float*)d_in[29];
    const float* fsr = (const float*)d_in[30];
    float* out = (float*)d_out;

    char* w = (char*)d_ws;
    auto alloc = [&](size_t bytes) { char* p = w; w += (bytes + 255) & ~(size_t)255; return p; };
    u16* ACCb    = (u16*)alloc(NS_ * 2);
    u16* FEATb   = (u16*)alloc(NS_ * 2);
    u16* Hb      = (u16*)alloc(NS_ * 2);
    u16* MINb    = (u16*)alloc(NS_ * 2);
    u16* MOUTb   = (u16*)alloc(NS_ * 2);
    u16* GIHb    = (u16*)alloc(NS_ * 8);    // N x 512
    u16* AXb     = GIHb;                    // aliases: GIH dead after gru
    u16* RHG     = GIHb + NS_;
    u16* ZG      = GIHb + 2 * NS_;
    u16* FUb     = MINb;                    // MINb dead after GIH gemm
    u16* embb    = (u16*)alloc((long long)V_ * 128 * 2);
    u16* srb     = (u16*)alloc(B_ * 128 * 2);
    u16* BM1t    = (u16*)alloc(512 * 128 * 2);
    u16* BM2t    = (u16*)alloc(512 * 128 * 2);
    u16* BM3t    = (u16*)alloc(512 * 128 * 2);
    u16* Brz1    = (u16*)alloc(256 * 128 * 2);
    u16* Brz2    = (u16*)alloc(256 * 128 * 2);
    u16* Bu1     = (u16*)alloc(128 * 128 * 2);
    u16* Bu2     = (u16*)alloc(128 * 128 * 2);
    u16* Bfc     = (u16*)alloc(128 * 128 * 2);
    float* b512  = (float*)alloc(512 * 4);
    float* brz   = (float*)alloc(256 * 4);
    float* bu    = (float*)alloc(128 * 4);
    float* dtp   = (float*)alloc(64 * 4);
    float* rnv   = (float*)alloc((long long)V_ * 4);
    float* rowsumP = (float*)alloc((long long)B_ * NBN_P * 4);
    float* logz  = (float*)alloc(B_ * 4);
    float* csr_nrm = (float*)alloc(3LL * B_ * P_ * 4);
    int* csr_soff  = (int*)alloc(3LL * B_ * 64 * 4);
    int* csr_snbr  = (int*)alloc(3LL * B_ * 100 * 4);

    k_embcv<<<(V_ + 3) / 4, 256, 0, stream>>>(emb, embb, rnv);
    k_dtmax<<<1, 1024, 0, stream>>>(et, dtp);
    k_csr<<<3 * B_, 64, 0, stream>>>(esrc, edst, et, dtp, csr_nrm, csr_soff, csr_snbr);
    k_feat0<<<N_ / 4, 256, 0, stream>>>(embb, rnv, iid, FEATb);

    // ---- stage A ----
    k_aggA_g<<<B_, 256, 0, stream>>>(esrc, edst, ew, FEATb, MINb, MOUTb);
    k_prec_all<<<1026, 256, 0, stream>>>(W1, W2, wih, whh, bih, bhh,
                                         Wxr, Wxz, Whr, Whz, bxr, bxz, bhr, bhz,
                                         Wxh, Whh, bxh, bhh2, fcu,
                                         BM1t, BM2t, BM3t, Brz1, Brz2, Bu1, Bu2, Bfc,
                                         b512, brz, bu);
    k_mm<3, 0><<<1600, 256, 0, stream>>>(MINb, MOUTb, FEATb, BM1t, BM2t, BM3t, b512, GIHb, 512, 4);
    k_gru2<<<N_ / 4, 256, 0, stream>>>(GIHb, FEATb, Hb);

    // ---- stage B: RK4, one fused kernel per stage (512-thread blocks) ----
    // (mask, h_is_x, axmode, accw, hfac, first)
    k_fstep<0><<<B_, 512, 0, stream>>>(csr_nrm, csr_soff, csr_snbr, 0, dtp, 1, 0,
                                       FEATb, Hb, AXb, RHG, ZG, ACCb,
                                       Brz1, Brz2, brz, Bu1, Bu2, bu, 1.f, 0.5f, 1);
    k_fstep<0><<<B_, 512, 0, stream>>>(csr_nrm, csr_soff, csr_snbr, 1, dtp, 0, 1,
                                       FEATb, Hb, AXb, RHG, ZG, ACCb,
                                       Brz1, Brz2, brz, Bu1, Bu2, bu, 2.f, 0.5f, 0);
    k_fstep<0><<<B_, 512, 0, stream>>>(csr_nrm, csr_soff, csr_snbr, 1, dtp, 0, 2,
                                       FEATb, Hb, AXb, RHG, ZG, ACCb,
                                       Brz1, Brz2, brz, Bu1, Bu2, bu, 2.f, 1.0f, 0);
    k_fstep<1><<<B_, 512, 0, stream>>>(csr_nrm, csr_soff, csr_snbr, 2, dtp, 0, 0,
                                       FEATb, Hb, AXb, RHG, ZG, ACCb,
                                       Brz1, Brz2, brz, Bu1, Bu2, bu, 1.f, 0.0f, 0);

    // ---- readout ----
    k_mm<1, 0><<<400, 256, 0, stream>>>(FEATb, nullptr, nullptr, Bfc, nullptr, nullptr,
                                        nullptr, FUb, 128, 1);
    k_readout<<<B_, 256, 0, stream>>>(FEATb, FUb, last, fvw, fvbv, fce, fsr, srb);

    k_logits<0><<<3136, 256, 0, stream>>>(srb, embb, rnv, rowsumP, nullptr, nullptr);
    k_rsum<<<8, 256, 0, stream>>>(rowsumP, logz);
    k_logits<1><<<3136, 256, 0, stream>>>(srb, embb, rnv, nullptr, logz, out);
}